// Round 1
// baseline (650.930 us; speedup 1.0000x reference)
//
#include <hip/hip_runtime.h>
#include <hip/hip_fp16.h>
#include <math.h>

#define EPS 1e-5f
#define N_GRAPHS 128

__device__ __forceinline__ float sigmoidf_(float x) {
    return __fdividef(1.0f, 1.0f + __expf(-x));
}

// ---------------------------------------------------------------------------
// Fused prep: block-range partition.
//  [0,256):  deg histogram      [256,320): fuse_w layer0 (K=128)
//  [320,384): fuse_w layer1 (K=64)        [384,400): per-graph counts
// ---------------------------------------------------------------------------
__device__ __forceinline__ void fuse_w_body(
    int b0, int blk, int tid,
    const float* __restrict__ Wk, const float* __restrict__ bk,
    const float* __restrict__ Wq, const float* __restrict__ bq,
    const float* __restrict__ Wv, const float* __restrict__ bv,
    const float* __restrict__ Ws, const float* __restrict__ cbv,
    float* __restrict__ Wf, float* __restrict__ bf, int K)
{
    int t = (blk - b0) * 256 + tid;
    int total = K * 256;
    for (int i = t; i < total; i += 64 * 256) {
        int k = i >> 8, c = i & 255;
        const float* W;
        int cc;
        if (c < 64)       { W = Wk; cc = c; }
        else if (c < 128) { W = Ws; cc = c - 64; }
        else { int j = c - 128; cc = j >> 1; W = (j & 1) ? Wv : Wq; }
        Wf[i] = W[k * 64 + cc];
    }
    if (t < 256) {
        int c = t;
        const float* b;
        int cc;
        if (c < 64)       { b = bk;  cc = c; }
        else if (c < 128) { b = cbv; cc = c - 64; }
        else { int j = c - 128; cc = j >> 1; b = (j & 1) ? bv : bq; }
        bf[t] = b[cc];
    }
}

__global__ __launch_bounds__(256) void prep_kernel(
    const int* __restrict__ ei, int* __restrict__ deg, int E,
    const int* __restrict__ batch, float* __restrict__ counts, int N,
    const float* __restrict__ Wk0, const float* __restrict__ bk0,
    const float* __restrict__ Wq0, const float* __restrict__ bq0,
    const float* __restrict__ Wv0, const float* __restrict__ bv0,
    const float* __restrict__ Ws0, const float* __restrict__ cb0,
    float* __restrict__ Wf0, float* __restrict__ bf0,
    const float* __restrict__ Wk1, const float* __restrict__ bk1,
    const float* __restrict__ Wq1, const float* __restrict__ bq1,
    const float* __restrict__ Wv1, const float* __restrict__ bv1,
    const float* __restrict__ Ws1, const float* __restrict__ cb1,
    float* __restrict__ Wf1, float* __restrict__ bf1)
{
    const int blk = blockIdx.x;
    const int tid = threadIdx.x;
    if (blk < 256) {
        int t = blk * 256 + tid;
        for (int e = t; e < E; e += 256 * 256) atomicAdd(&deg[ei[E + e]], 1);
    } else if (blk < 320) {
        fuse_w_body(256, blk, tid, Wk0, bk0, Wq0, bq0, Wv0, bv0, Ws0, cb0,
                    Wf0, bf0, 128);
    } else if (blk < 384) {
        fuse_w_body(320, blk, tid, Wk1, bk1, Wq1, bq1, Wv1, bv1, Ws1, cb1,
                    Wf1, bf1, 64);
    } else {
        const int t = (blk - 384) * 256 + tid;
        const int T = 16 * 256;
        const int chunk = (N + T - 1) / T;
        const int a = t * chunk;
        const int b = min(N, a + chunk);
        int cur = -1;
        float c = 0.0f;
        for (int n = a; n < b; ++n) {
            int gi = batch[n];
            if (gi != cur) {
                if (cur >= 0) atomicAdd(&counts[cur], c);
                cur = gi;
                c = 0.0f;
            }
            c += 1.0f;
        }
        if (cur >= 0) atomicAdd(&counts[cur], c);
    }
}

// ---------------------------------------------------------------------------
// Projection: LDS-tiled fp32 GEMM, fused cols. Tile M=64 x N=128 (blockIdx&1).
// nb=0 -> fp32 [k|s] to Y2[N][128]; nb=1 -> fp16-packed (q,v) to QV[N][64].
// AFF: BN affine computed in-kernel from stats/g/be, applied while staging X.
// ---------------------------------------------------------------------------
template <int K, bool AFF>
__global__ __launch_bounds__(256) void proj_kernel(
    const float* __restrict__ X, const float* __restrict__ Wf,
    const float* __restrict__ bf,
    const float* __restrict__ stats, const float* __restrict__ g,
    const float* __restrict__ be, float invN,
    float* __restrict__ Y2, unsigned* __restrict__ QV, int N)
{
    __shared__ __attribute__((aligned(16))) float As[16][72];
    __shared__ __attribute__((aligned(16))) float Bs[16][128];
    const int tid = threadIdx.x;
    const int nb = blockIdx.x & 1;
    const int n0 = (blockIdx.x >> 1) * 64;
    const int cg = tid & 31;
    const int mg = tid >> 5;
    const int ar = tid >> 2, akq = (tid & 3) * 4;
    const int bk_ = tid >> 4, bcol = (tid & 15) * 8;

    float acc[8][4];
#pragma unroll
    for (int r = 0; r < 8; ++r)
#pragma unroll
        for (int j = 0; j < 4; ++j) acc[r][j] = 0.0f;

    for (int k0 = 0; k0 < K; k0 += 16) {
        float4 av4 = make_float4(0.f, 0.f, 0.f, 0.f);
        int row = n0 + ar;
        if (row < N) av4 = *(const float4*)&X[(size_t)row * K + k0 + akq];
        if constexpr (AFF) {
            float a4[4], b4[4];
#pragma unroll
            for (int i = 0; i < 4; ++i) {
                int c = k0 + akq + i;
                float m = stats[c] * invN;
                float vv = stats[64 + c] * invN - m * m;
                float rs = rsqrtf(vv + EPS) * g[c];
                a4[i] = rs;
                b4[i] = be[c] - m * rs;
            }
            av4.x = fmaf(av4.x, a4[0], b4[0]);
            av4.y = fmaf(av4.y, a4[1], b4[1]);
            av4.z = fmaf(av4.z, a4[2], b4[2]);
            av4.w = fmaf(av4.w, a4[3], b4[3]);
        }
        const float4 b0 = *(const float4*)&Wf[(size_t)(k0 + bk_) * 256 + nb * 128 + bcol];
        const float4 b1 = *(const float4*)&Wf[(size_t)(k0 + bk_) * 256 + nb * 128 + bcol + 4];
        __syncthreads();
        As[akq + 0][ar] = av4.x;
        As[akq + 1][ar] = av4.y;
        As[akq + 2][ar] = av4.z;
        As[akq + 3][ar] = av4.w;
        *(float4*)&Bs[bk_][bcol] = b0;
        *(float4*)&Bs[bk_][bcol + 4] = b1;
        __syncthreads();
#pragma unroll
        for (int kk = 0; kk < 16; ++kk) {
            float4 a0 = *(const float4*)&As[kk][8 * mg];
            float4 a1 = *(const float4*)&As[kk][8 * mg + 4];
            float4 bv = *(const float4*)&Bs[kk][4 * cg];
            float am[8] = {a0.x, a0.y, a0.z, a0.w, a1.x, a1.y, a1.z, a1.w};
#pragma unroll
            for (int r = 0; r < 8; ++r) {
                acc[r][0] = fmaf(am[r], bv.x, acc[r][0]);
                acc[r][1] = fmaf(am[r], bv.y, acc[r][1]);
                acc[r][2] = fmaf(am[r], bv.z, acc[r][2]);
                acc[r][3] = fmaf(am[r], bv.w, acc[r][3]);
            }
        }
    }

    float4 bias;
    bias.x = bf[nb * 128 + 4 * cg + 0];
    bias.y = bf[nb * 128 + 4 * cg + 1];
    bias.z = bf[nb * 128 + 4 * cg + 2];
    bias.w = bf[nb * 128 + 4 * cg + 3];
    const int nn = min(64, N - n0);
    if (nb == 0) {
#pragma unroll
        for (int r = 0; r < 8; ++r) {
            int row = 8 * mg + r;
            if (row < nn) {
                float4 o;
                o.x = acc[r][0] + bias.x;
                o.y = acc[r][1] + bias.y;
                o.z = acc[r][2] + bias.z;
                o.w = acc[r][3] + bias.w;
                *(float4*)&Y2[(size_t)(n0 + row) * 128 + 4 * cg] = o;
            }
        }
    } else {
#pragma unroll
        for (int r = 0; r < 8; ++r) {
            int row = 8 * mg + r;
            if (row < nn) {
                __half2 p0 = __floats2half2_rn(acc[r][0] + bias.x, acc[r][1] + bias.y);
                __half2 p1 = __floats2half2_rn(acc[r][2] + bias.z, acc[r][3] + bias.w);
                uint2 u;
                u.x = *reinterpret_cast<unsigned*>(&p0);
                u.y = *reinterpret_cast<unsigned*>(&p1);
                *(uint2*)&QV[(size_t)(n0 + row) * 64 + 2 * cg] = u;
            }
        }
    }
}

// ---------------------------------------------------------------------------
// CSR scans + scatter.
// ---------------------------------------------------------------------------
__global__ __launch_bounds__(256) void scan1_kernel(
    const int* __restrict__ deg, int* __restrict__ rp1loc,
    int* __restrict__ psum, int N)
{
    __shared__ int s[256];
    const int b = blockIdx.x;
    const int base = b * 1024;
    const int t = threadIdx.x;
    int v[4], sum = 0;
#pragma unroll
    for (int i = 0; i < 4; ++i) {
        int idx = base + t * 4 + i;
        v[i] = (idx < N) ? deg[idx] : 0;
        sum += v[i];
    }
    s[t] = sum;
    __syncthreads();
    for (int off = 1; off < 256; off <<= 1) {
        int x = (t >= off) ? s[t - off] : 0;
        __syncthreads();
        s[t] += x;
        __syncthreads();
    }
    int run = s[t] - sum;
#pragma unroll
    for (int i = 0; i < 4; ++i) {
        run += v[i];
        int idx = base + t * 4 + i;
        if (idx < N) rp1loc[idx] = run;
    }
    if (t == 255) psum[b] = s[255];
}

__global__ __launch_bounds__(256) void scan2_kernel(int* __restrict__ psum, int NBLK)
{
    __shared__ int s[256];
    int t = threadIdx.x;
    int c = (t < NBLK) ? psum[t] : 0;
    s[t] = c;
    __syncthreads();
    for (int off = 1; off < 256; off <<= 1) {
        int x = (t >= off) ? s[t - off] : 0;
        __syncthreads();
        s[t] += x;
        __syncthreads();
    }
    if (t < NBLK) psum[t] = s[t] - c;
}

__global__ __launch_bounds__(256) void scan3_kernel(
    const int* __restrict__ rp1loc, const int* __restrict__ psum,
    int* __restrict__ rowptr, int* __restrict__ cursor, int N)
{
    int t = blockIdx.x * 256 + threadIdx.x;
    int T = gridDim.x * 256;
    for (int i = t; i < N; i += T) {
        rowptr[i + 1] = rp1loc[i] + psum[i >> 10];
        cursor[i] = (i == 0) ? 0 : rp1loc[i - 1] + psum[(i - 1) >> 10];
    }
    if (t == 0) rowptr[0] = 0;
}

__global__ __launch_bounds__(256) void scatter_kernel(
    const int* __restrict__ ei, int* __restrict__ cursor,
    int* __restrict__ col, int E)
{
    int t = blockIdx.x * 256 + threadIdx.x;
    int T = gridDim.x * 256;
    for (int e = t; e < E; e += T) {
        int d = ei[E + e];
        int pos = atomicAdd(&cursor[d], 1);
        col[pos] = ei[e];
    }
}

// ---------------------------------------------------------------------------
// Aggregation v8: streaming edge pipeline. A wave's contiguous node chunk
// maps to a contiguous CSR edge range [rowptr[nA], rowptr[nB]). Edges are
// consumed in batches of 16 IRRESPECTIVE of node boundaries: 16 uniform col
// reads -> SGPRs -> 16 saddr gathers all in flight before any math (4x the
// memory-level parallelism of v7's 4-deep groups). Node boundaries are
// handled by a wave-uniform scalar check per edge.
// Fuses sigmoid + BN channel stats + per-graph raw-y sums.
// ---------------------------------------------------------------------------
__global__ __launch_bounds__(256) void agg_kernel(
    const int* __restrict__ rowptr, const int* __restrict__ col,
    const float* __restrict__ Y2, const unsigned* __restrict__ QV,
    const int* __restrict__ batch,
    float* __restrict__ H, float* __restrict__ stats,
    float* __restrict__ gsumy, int N)
{
    const int tid = threadIdx.x;
    const int lane = tid & 63;
    const int wid = __builtin_amdgcn_readfirstlane(
        (int)((blockIdx.x * blockDim.x + tid) >> 6));
    const int NW = (gridDim.x * blockDim.x) >> 6;
    const int chunk = (N + NW - 1) / NW;
    const int nA = wid * chunk;
    const int nB = min(N, nA + chunk);
    const float L2E = 1.44269504f;

    float st1 = 0.0f, st2 = 0.0f, gacc = 0.0f;
    int cur = -1;

    if (nA < nB) {
        int n = nA;
        int e = __builtin_amdgcn_readfirstlane(rowptr[nA]);
        const int eB = __builtin_amdgcn_readfirstlane(rowptr[nB]);
        int r1 = __builtin_amdgcn_readfirstlane(rowptr[nA + 1]);
        float acc = Y2[(size_t)n * 128 + 64 + lane];
        float nkl = Y2[(size_t)n * 128 + lane] * (-L2E);

        // Finish current node n (sigmoid, H write, stats, per-graph sum),
        // then advance to n+1 and load its y-row. Wave-uniform control.
        auto finishAdvance = [&]() {
            float y = __builtin_amdgcn_rcpf(
                1.0f + __builtin_amdgcn_exp2f(acc * (-L2E)));
            H[(size_t)n * 64 + lane] = y;
            st1 += y;
            st2 += y * y;
            int gi = __builtin_amdgcn_readfirstlane(batch[n]);
            if (gi != cur) {
                if (cur >= 0) atomicAdd(&gsumy[cur * 64 + lane], gacc);
                gacc = 0.0f;
                cur = gi;
            }
            gacc += y;
            ++n;
            if (n < nB) {
                r1 = __builtin_amdgcn_readfirstlane(rowptr[n + 1]);
                acc = Y2[(size_t)n * 128 + 64 + lane];
                nkl = Y2[(size_t)n * 128 + lane] * (-L2E);
            }
        };

#define RFL_(v, i) int v = __builtin_amdgcn_readfirstlane(col[e + i]);
#define GATH_(u, v) unsigned u = QV[((size_t)v << 6) + lane];
#define EDGE_(u, i)                                                          \
    {                                                                        \
        while (e + i == r1) finishAdvance();                                 \
        unsigned uu_ = u;                                                    \
        float2 f_ = __half22float2(*reinterpret_cast<__half2*>(&uu_));       \
        float ex_ = __builtin_amdgcn_exp2f(fmaf(f_.x, -L2E, nkl));           \
        acc = fmaf(__builtin_amdgcn_rcpf(1.0f + ex_), f_.y, acc);            \
    }

        while (e + 16 <= eB) {
            RFL_(sa_, 0)  RFL_(sb_, 1)  RFL_(sc_, 2)  RFL_(sd_, 3)
            RFL_(se_, 4)  RFL_(sf_, 5)  RFL_(sg_, 6)  RFL_(sh_, 7)
            RFL_(si_, 8)  RFL_(sj_, 9)  RFL_(sk_, 10) RFL_(sl_, 11)
            RFL_(sm_, 12) RFL_(sn_, 13) RFL_(so_, 14) RFL_(sp_, 15)
            GATH_(ua_, sa_) GATH_(ub_, sb_) GATH_(uc_, sc_) GATH_(ud_, sd_)
            GATH_(ue_, se_) GATH_(uf_, sf_) GATH_(ug_, sg_) GATH_(uh_, sh_)
            GATH_(ui_, si_) GATH_(uj_, sj_) GATH_(uk_, sk_) GATH_(ul_, sl_)
            GATH_(um_, sm_) GATH_(un_, sn_) GATH_(uo_, so_) GATH_(up_, sp_)
            EDGE_(ua_, 0)  EDGE_(ub_, 1)  EDGE_(uc_, 2)  EDGE_(ud_, 3)
            EDGE_(ue_, 4)  EDGE_(uf_, 5)  EDGE_(ug_, 6)  EDGE_(uh_, 7)
            EDGE_(ui_, 8)  EDGE_(uj_, 9)  EDGE_(uk_, 10) EDGE_(ul_, 11)
            EDGE_(um_, 12) EDGE_(un_, 13) EDGE_(uo_, 14) EDGE_(up_, 15)
            e += 16;
        }
        for (; e < eB; ++e) {
            while (e == r1) finishAdvance();
            int sx_ = __builtin_amdgcn_readfirstlane(col[e]);
            unsigned ux_ = QV[((size_t)sx_ << 6) + lane];
            float2 f_ = __half22float2(*reinterpret_cast<__half2*>(&ux_));
            float ex_ = __builtin_amdgcn_exp2f(fmaf(f_.x, -L2E, nkl));
            acc = fmaf(__builtin_amdgcn_rcpf(1.0f + ex_), f_.y, acc);
        }
        // Drain remaining nodes (incl. trailing zero-degree nodes).
        while (n < nB) finishAdvance();
#undef RFL_
#undef GATH_
#undef EDGE_
    }
    if (cur >= 0) atomicAdd(&gsumy[cur * 64 + lane], gacc);

    __shared__ float red1[4][64], red2[4][64];
    const int w = tid >> 6;
    red1[w][lane] = st1;
    red2[w][lane] = st2;
    __syncthreads();
    if (tid < 64) {
        float a = red1[0][lane] + red1[1][lane] + red1[2][lane] + red1[3][lane];
        float c = red2[0][lane] + red2[1][lane] + red2[2][lane] + red2[3][lane];
        atomicAdd(&stats[lane], a);
        atomicAdd(&stats[64 + lane], c);
    }
}

// ---------------------------------------------------------------------------
// Head 1: reconstruct BN'd per-graph sums from raw-y sums via the affine
//   sum_v = rs*sum_y + cnt*(be - m*rs),  mean = sum_v / max(cnt,1)
// ---------------------------------------------------------------------------
__global__ __launch_bounds__(128) void head1_kernel(
    const float* __restrict__ gsumy0, const float* __restrict__ gsumy1,
    const float* __restrict__ counts,
    const float* __restrict__ stats0, const float* __restrict__ stats1,
    const float* __restrict__ g0, const float* __restrict__ be0,
    const float* __restrict__ g1, const float* __restrict__ be1,
    const float* __restrict__ Wh0, const float* __restrict__ bh0,
    float* __restrict__ t0, float* __restrict__ hstat0, float invN)
{
    const int gr = blockIdx.x;
    const int o = threadIdx.x;
    __shared__ float feat[256];

    const float* st = (o < 64) ? stats0 : stats1;
    const float* gg = (o < 64) ? g0 : g1;
    const float* bb = (o < 64) ? be0 : be1;
    const float* gs = (o < 64) ? gsumy0 : gsumy1;
    int c = o & 63;
    float m = st[c] * invN;
    float var = st[64 + c] * invN - m * m;
    float rs = rsqrtf(var + EPS) * gg[c];
    float off = bb[c] - m * rs;
    float cnt = counts[gr];
    float sv = rs * gs[gr * 64 + c] + cnt * off;
    float inv = __fdividef(1.0f, fmaxf(cnt, 1.0f));
    feat[o] = sv * inv;
    feat[128 + o] = sv;
    __syncthreads();

    float acc = bh0[o];
    for (int j = 0; j < 256; ++j) acc = fmaf(feat[j], Wh0[j * 128 + o], acc);
    float y = sigmoidf_(acc);
    t0[gr * 128 + o] = y;
    atomicAdd(&hstat0[o], y);
    atomicAdd(&hstat0[128 + o], y * y);
}

__global__ __launch_bounds__(64) void head2_kernel(
    const float* __restrict__ t0, const float* __restrict__ hstat0,
    const float* __restrict__ gh0, const float* __restrict__ beh0,
    const float* __restrict__ Wh1, const float* __restrict__ bh1,
    float* __restrict__ t1, float* __restrict__ hstat1)
{
    const int gr = blockIdx.x;
    const int o = threadIdx.x;
    __shared__ float bn0[128];
    const float invG = 1.0f / (float)N_GRAPHS;
    for (int j = o; j < 128; j += 64) {
        float m = hstat0[j] * invG;
        float v = hstat0[128 + j] * invG - m * m;
        bn0[j] = (t0[gr * 128 + j] - m) * rsqrtf(v + EPS) * gh0[j] + beh0[j];
    }
    __syncthreads();
    float acc = bh1[o];
    for (int j = 0; j < 128; ++j) acc = fmaf(bn0[j], Wh1[j * 64 + o], acc);
    float y = sigmoidf_(acc);
    t1[gr * 64 + o] = y;
    atomicAdd(&hstat1[o], y);
    atomicAdd(&hstat1[64 + o], y * y);
}

__global__ __launch_bounds__(64) void head3_kernel(
    const float* __restrict__ t1, const float* __restrict__ hstat1,
    const float* __restrict__ gh1, const float* __restrict__ beh1,
    const float* __restrict__ Wc, const float* __restrict__ bc,
    float* __restrict__ out)
{
    const int gr = blockIdx.x;
    const int o = threadIdx.x;
    const float invG = 1.0f / (float)N_GRAPHS;
    float m = hstat1[o] * invG;
    float v = hstat1[64 + o] * invG - m * m;
    float b = (t1[gr * 64 + o] - m) * rsqrtf(v + EPS) * gh1[o] + beh1[o];
    float p0 = b * Wc[o * 2];
    float p1 = b * Wc[o * 2 + 1];
#pragma unroll
    for (int off = 32; off > 0; off >>= 1) {
        p0 += __shfl_down(p0, off);
        p1 += __shfl_down(p1, off);
    }
    if (o == 0) {
        out[gr * 2] = p0 + bc[0];
        out[gr * 2 + 1] = p1 + bc[1];
    }
}

// ---------------------------------------------------------------------------
extern "C" void kernel_launch(void* const* d_in, const int* in_sizes, int n_in,
                              void* d_out, int out_size, void* d_ws, size_t ws_size,
                              hipStream_t stream)
{
    const float* x     = (const float*)d_in[0];
    const int*   ei    = (const int*)d_in[1];
    const int*   batch = (const int*)d_in[2];
    const int N = in_sizes[2];
    const int E = in_sizes[1] / 2;
    const int NCHUNK = (N + 1023) / 1024;

    const float *Wk0 = (const float*)d_in[3],  *bk0 = (const float*)d_in[4];
    const float *Wq0 = (const float*)d_in[5],  *bq0 = (const float*)d_in[6];
    const float *Wv0 = (const float*)d_in[7],  *bv0 = (const float*)d_in[8];
    const float *Ws0 = (const float*)d_in[9],  *cb0 = (const float*)d_in[10];
    const float *g0  = (const float*)d_in[11], *be0 = (const float*)d_in[12];
    const float *Wk1 = (const float*)d_in[13], *bk1 = (const float*)d_in[14];
    const float *Wq1 = (const float*)d_in[15], *bq1 = (const float*)d_in[16];
    const float *Wv1 = (const float*)d_in[17], *bv1 = (const float*)d_in[18];
    const float *Ws1 = (const float*)d_in[19], *cb1 = (const float*)d_in[20];
    const float *g1  = (const float*)d_in[21], *be1 = (const float*)d_in[22];
    const float *Wh0 = (const float*)d_in[23], *bh0 = (const float*)d_in[24];
    const float *gh0 = (const float*)d_in[25], *beh0 = (const float*)d_in[26];
    const float *Wh1 = (const float*)d_in[27], *bh1 = (const float*)d_in[28];
    const float *gh1 = (const float*)d_in[29], *beh1 = (const float*)d_in[30];
    const float *Wc  = (const float*)d_in[31], *bc  = (const float*)d_in[32];

    float*    ws = (float*)d_ws;
    float*    Y2 = ws;                          // N*128 fp32 [k|s]
    unsigned* QV = (unsigned*)(Y2 + (size_t)N * 128);  // N*64 packed fp16 q|v
    float*    H  = (float*)(QV + (size_t)N * 64);      // N*64 fp32 (raw y)
    int*   col     = (int*)(H + (size_t)N * 64);       // E
    int*   rowptr  = col + E;             // N+1
    int*   rp1loc  = rowptr + N + 1;      // N
    int*   cursor  = rp1loc + N;          // N
    int*   psum    = cursor + N;          // 256
    float* Wf0  = (float*)(psum + 256);   // 128*256
    float* bf0  = Wf0 + 128 * 256;        // 256
    float* Wf1  = bf0 + 256;              // 64*256
    float* bf1  = Wf1 + 64 * 256;         // 256
    int*   deg     = (int*)(bf1 + 256);   // N    <-- zero zone starts here
    float* gsumy0 = (float*)(deg + N);    // 128*64
    float* gsumy1 = gsumy0 + 128 * 64;    // 128*64
    float* counts = gsumy1 + 128 * 64;    // 128
    float* stats0 = counts + 128;         // 128
    float* stats1 = stats0 + 128;         // 128
    float* hstat0 = stats1 + 128;         // 256
    float* hstat1 = hstat0 + 256;         // 128
    size_t zbytes = (size_t)N * sizeof(int) +
                    (size_t)(128 * 64 * 2 + 128 * 3 + 256 + 128) * sizeof(float);
    float* t0 = hstat1 + 128;             // 128*128
    float* t1 = t0 + 128 * 128;           // 128*64

    hipMemsetAsync(deg, 0, zbytes, stream);

    // ---- fused prep (deg + counts + weight fusion) ----
    prep_kernel<<<400, 256, 0, stream>>>(
        ei, deg, E, batch, counts, N,
        Wk0, bk0, Wq0, bq0, Wv0, bv0, Ws0, cb0, Wf0, bf0,
        Wk1, bk1, Wq1, bq1, Wv1, bv1, Ws1, cb1, Wf1, bf1);
    scan1_kernel<<<NCHUNK, 256, 0, stream>>>(deg, rp1loc, psum, N);
    scan2_kernel<<<1, 256, 0, stream>>>(psum, NCHUNK);
    scan3_kernel<<<256, 256, 0, stream>>>(rp1loc, psum, rowptr, cursor, N);
    scatter_kernel<<<512, 256, 0, stream>>>(ei, cursor, col, E);

    const float invN = 1.0f / (float)N;
    const int projBlocks = ((N + 63) / 64) * 2;

    // ---- layer 0 ----
    proj_kernel<128, false><<<projBlocks, 256, 0, stream>>>(
        x, Wf0, bf0, nullptr, nullptr, nullptr, invN, Y2, QV, N);
    agg_kernel<<<2048, 256, 0, stream>>>(rowptr, col, Y2, QV, batch,
                                         H, stats0, gsumy0, N);

    // ---- layer 1 (BN affine computed in-kernel from stats0) ----
    proj_kernel<64, true><<<projBlocks, 256, 0, stream>>>(
        H, Wf1, bf1, stats0, g0, be0, invN, Y2, QV, N);
    agg_kernel<<<2048, 256, 0, stream>>>(rowptr, col, Y2, QV, batch,
                                         H, stats1, gsumy1, N);

    // ---- head ----
    head1_kernel<<<128, 128, 0, stream>>>(gsumy0, gsumy1, counts,
                                          stats0, stats1, g0, be0, g1, be1,
                                          Wh0, bh0, t0, hstat0, invN);
    head2_kernel<<<128, 64, 0, stream>>>(t0, hstat0, gh0, beh0, Wh1, bh1, t1, hstat1);
    head3_kernel<<<128, 64, 0, stream>>>(t1, hstat1, gh1, beh1, Wc, bc, (float*)d_out);
}

// Round 3
// 581.497 us; speedup vs baseline: 1.1194x; 1.1194x over previous
//
#include <hip/hip_runtime.h>
#include <hip/hip_fp16.h>
#include <math.h>

#define EPS 1e-5f
#define N_GRAPHS 128

typedef __attribute__((ext_vector_type(8))) short s8v;
typedef __attribute__((ext_vector_type(4))) float f4v;

__device__ __forceinline__ float sigmoidf_(float x) {
    return __fdividef(1.0f, 1.0f + __expf(-x));
}

__device__ __forceinline__ short bf16rne(float f) {
    unsigned u = __builtin_bit_cast(unsigned, f);
    unsigned r = (u + 0x7FFFu + ((u >> 16) & 1u)) >> 16;
    return (short)r;
}
__device__ __forceinline__ float bf16tof(short h) {
    unsigned u = ((unsigned)(unsigned short)h) << 16;
    return __builtin_bit_cast(float, u);
}

// ---------------------------------------------------------------------------
// Fused prep: block-range partition.
//  [0,256):  deg histogram      [256,320): fuse_w layer0 (K=128)
//  [320,384): fuse_w layer1 (K=64)        [384,400): per-graph counts
// Weights are fused (cols: [0,64)=Wk, [64,128)=Ws, [128,256)=interleaved
// (Wq,Wv) pairs), transposed to [col][k], and SPLIT into hi/lo bf16 so the
// MFMA path reproduces fp32 accuracy (3-product split-bf16).
// ---------------------------------------------------------------------------
__device__ __forceinline__ void fuse_w_body(
    int b0, int blk, int tid,
    const float* __restrict__ Wk, const float* __restrict__ bk,
    const float* __restrict__ Wq, const float* __restrict__ bq,
    const float* __restrict__ Wv, const float* __restrict__ bv,
    const float* __restrict__ Ws, const float* __restrict__ cbv,
    short* __restrict__ BTh, short* __restrict__ BTl,
    float* __restrict__ bf, int K)
{
    int t = (blk - b0) * 256 + tid;
    int total = K * 256;
    for (int i = t; i < total; i += 64 * 256) {
        int k = i >> 8, c = i & 255;
        const float* W;
        int cc;
        if (c < 64)       { W = Wk; cc = c; }
        else if (c < 128) { W = Ws; cc = c - 64; }
        else { int j = c - 128; cc = j >> 1; W = (j & 1) ? Wv : Wq; }
        float wv = W[k * 64 + cc];
        short h = bf16rne(wv);
        short l = bf16rne(wv - bf16tof(h));
        BTh[(size_t)c * K + k] = h;
        BTl[(size_t)c * K + k] = l;
    }
    if (t < 256) {
        int c = t;
        const float* b;
        int cc;
        if (c < 64)       { b = bk;  cc = c; }
        else if (c < 128) { b = cbv; cc = c - 64; }
        else { int j = c - 128; cc = j >> 1; b = (j & 1) ? bv : bq; }
        bf[t] = b[cc];
    }
}

__global__ __launch_bounds__(256) void prep_kernel(
    const int* __restrict__ ei, int* __restrict__ deg, int E,
    const int* __restrict__ batch, float* __restrict__ counts, int N,
    const float* __restrict__ Wk0, const float* __restrict__ bk0,
    const float* __restrict__ Wq0, const float* __restrict__ bq0,
    const float* __restrict__ Wv0, const float* __restrict__ bv0,
    const float* __restrict__ Ws0, const float* __restrict__ cb0,
    short* __restrict__ BT0h, short* __restrict__ BT0l, float* __restrict__ bf0,
    const float* __restrict__ Wk1, const float* __restrict__ bk1,
    const float* __restrict__ Wq1, const float* __restrict__ bq1,
    const float* __restrict__ Wv1, const float* __restrict__ bv1,
    const float* __restrict__ Ws1, const float* __restrict__ cb1,
    short* __restrict__ BT1h, short* __restrict__ BT1l, float* __restrict__ bf1)
{
    const int blk = blockIdx.x;
    const int tid = threadIdx.x;
    if (blk < 256) {
        int t = blk * 256 + tid;
        for (int e = t; e < E; e += 256 * 256) atomicAdd(&deg[ei[E + e]], 1);
    } else if (blk < 320) {
        fuse_w_body(256, blk, tid, Wk0, bk0, Wq0, bq0, Wv0, bv0, Ws0, cb0,
                    BT0h, BT0l, bf0, 128);
    } else if (blk < 384) {
        fuse_w_body(320, blk, tid, Wk1, bk1, Wq1, bq1, Wv1, bv1, Ws1, cb1,
                    BT1h, BT1l, bf1, 64);
    } else {
        const int t = (blk - 384) * 256 + tid;
        const int T = 16 * 256;
        const int chunk = (N + T - 1) / T;
        const int a = t * chunk;
        const int b = min(N, a + chunk);
        int cur = -1;
        float c = 0.0f;
        for (int n = a; n < b; ++n) {
            int gi = batch[n];
            if (gi != cur) {
                if (cur >= 0) atomicAdd(&counts[cur], c);
                cur = gi;
                c = 0.0f;
            }
            c += 1.0f;
        }
        if (cur >= 0) atomicAdd(&counts[cur], c);
    }
}

// ---------------------------------------------------------------------------
// Projection v2: split-bf16 MFMA GEMM (3 products: AhBh + AhBl + AlBh, fp32
// accumulate -> ~fp32 accuracy). Tile: M=64 rows x N=256 fused cols per
// block; 4 waves, each owning 64 cols (4 colblocks) x 64 rows (4 rowblocks).
// A staged fp32->split-bf16 in LDS; B^T (bf16 split, built in prep) read
// directly from global (L2-hot, 96 KB total).
// Fragment layout (m91/m97-verified): A/B: 8 contiguous k per lane,
// m|n = lane&15, kgroup = lane>>4; C/D: col = lane&15, row = (lane>>4)*4+j.
// Epilogue: cols<128 -> fp32 Y2; cols>=128 -> (q,v) col pairs packed to
// fp16x2 QV via __shfl_xor(val,1) (even lane holds q, odd holds v).
// ---------------------------------------------------------------------------
template <int K, bool AFF>
__global__ __launch_bounds__(256) void proj_mfma_kernel(
    const float* __restrict__ X,
    const short* __restrict__ BTh, const short* __restrict__ BTl,
    const float* __restrict__ bf,
    const float* __restrict__ stats, const float* __restrict__ g,
    const float* __restrict__ be, float invN,
    float* __restrict__ Y2, unsigned* __restrict__ QV, int N)
{
    __shared__ __attribute__((aligned(16))) short Ah_s[64 * 40];
    __shared__ __attribute__((aligned(16))) short Al_s[64 * 40];
    const int tid = threadIdx.x;
    const int lane = tid & 63;
    const int w = tid >> 6;
    const int n0 = blockIdx.x * 64;
    const int m = lane & 15;
    const int kg = lane >> 4;
    const int srow = tid >> 2;
    const int skq = (tid & 3) * 8;

    f4v acc[4][4];
#pragma unroll
    for (int rb = 0; rb < 4; ++rb)
#pragma unroll
        for (int cc = 0; cc < 4; ++cc) {
            acc[rb][cc][0] = 0.0f; acc[rb][cc][1] = 0.0f;
            acc[rb][cc][2] = 0.0f; acc[rb][cc][3] = 0.0f;
        }

    for (int k0 = 0; k0 < K; k0 += 32) {
        // B fragments from global (L2-hot, reused by every block)
        s8v Bh[4], Bl[4];
#pragma unroll
        for (int cc = 0; cc < 4; ++cc) {
            const int colb = (w * 4 + cc) * 16 + m;
            const size_t off = (size_t)colb * K + k0 + kg * 8;
            Bh[cc] = *(const s8v*)&BTh[off];
            Bl[cc] = *(const s8v*)&BTl[off];
        }
        // Stage A: fp32 -> split bf16 -> LDS
        __syncthreads();
        {
            float xv[8];
            const int row = n0 + srow;
            if (row < N) {
                float4 x0 = *(const float4*)&X[(size_t)row * K + k0 + skq];
                float4 x1 = *(const float4*)&X[(size_t)row * K + k0 + skq + 4];
                xv[0] = x0.x; xv[1] = x0.y; xv[2] = x0.z; xv[3] = x0.w;
                xv[4] = x1.x; xv[5] = x1.y; xv[6] = x1.z; xv[7] = x1.w;
            } else {
#pragma unroll
                for (int i = 0; i < 8; ++i) xv[i] = 0.0f;
            }
            if constexpr (AFF) {
#pragma unroll
                for (int i = 0; i < 8; ++i) {
                    int c = k0 + skq + i;
                    float mm = stats[c] * invN;
                    float vv = stats[64 + c] * invN - mm * mm;
                    float rs = rsqrtf(vv + EPS) * g[c];
                    xv[i] = fmaf(xv[i], rs, be[c] - mm * rs);
                }
            }
            s8v vh, vl;
#pragma unroll
            for (int i = 0; i < 8; ++i) {
                short h = bf16rne(xv[i]);
                vh[i] = h;
                vl[i] = bf16rne(xv[i] - bf16tof(h));
            }
            *(s8v*)&Ah_s[srow * 40 + skq] = vh;
            *(s8v*)&Al_s[srow * 40 + skq] = vl;
        }
        __syncthreads();
        // MFMA
#pragma unroll
        for (int rb = 0; rb < 4; ++rb) {
            const int aoff = (rb * 16 + m) * 40 + kg * 8;
            s8v Ah = *(const s8v*)&Ah_s[aoff];
            s8v Al = *(const s8v*)&Al_s[aoff];
#pragma unroll
            for (int cc = 0; cc < 4; ++cc) {
                acc[rb][cc] = __builtin_amdgcn_mfma_f32_16x16x32_bf16(
                    Ah, Bh[cc], acc[rb][cc], 0, 0, 0);
                acc[rb][cc] = __builtin_amdgcn_mfma_f32_16x16x32_bf16(
                    Ah, Bl[cc], acc[rb][cc], 0, 0, 0);
                acc[rb][cc] = __builtin_amdgcn_mfma_f32_16x16x32_bf16(
                    Al, Bh[cc], acc[rb][cc], 0, 0, 0);
            }
        }
    }

    // Epilogue
#pragma unroll
    for (int rb = 0; rb < 4; ++rb) {
#pragma unroll
        for (int cc = 0; cc < 4; ++cc) {
            const int colb = (w * 4 + cc) * 16 + m;
            const float bias = bf[colb];
#pragma unroll
            for (int j = 0; j < 4; ++j) {
                const int row = n0 + rb * 16 + kg * 4 + j;
                float val = acc[rb][cc][j] + bias;
                if (w < 2) {
                    if (row < N) Y2[(size_t)row * 128 + colb] = val;
                } else {
                    float pv = __shfl_xor(val, 1);
                    if (!(lane & 1) && row < N) {
                        __half2 h2 = __floats2half2_rn(val, pv);
                        QV[(size_t)row * 64 + ((colb - 128) >> 1)] =
                            *reinterpret_cast<unsigned*>(&h2);
                    }
                }
            }
        }
    }
}

// ---------------------------------------------------------------------------
// CSR scans + scatter.
// ---------------------------------------------------------------------------
__global__ __launch_bounds__(256) void scan1_kernel(
    const int* __restrict__ deg, int* __restrict__ rp1loc,
    int* __restrict__ psum, int N)
{
    __shared__ int s[256];
    const int b = blockIdx.x;
    const int base = b * 1024;
    const int t = threadIdx.x;
    int v[4], sum = 0;
#pragma unroll
    for (int i = 0; i < 4; ++i) {
        int idx = base + t * 4 + i;
        v[i] = (idx < N) ? deg[idx] : 0;
        sum += v[i];
    }
    s[t] = sum;
    __syncthreads();
    for (int off = 1; off < 256; off <<= 1) {
        int x = (t >= off) ? s[t - off] : 0;
        __syncthreads();
        s[t] += x;
        __syncthreads();
    }
    int run = s[t] - sum;
#pragma unroll
    for (int i = 0; i < 4; ++i) {
        run += v[i];
        int idx = base + t * 4 + i;
        if (idx < N) rp1loc[idx] = run;
    }
    if (t == 255) psum[b] = s[255];
}

__global__ __launch_bounds__(256) void scan2_kernel(int* __restrict__ psum, int NBLK)
{
    __shared__ int s[256];
    int t = threadIdx.x;
    int c = (t < NBLK) ? psum[t] : 0;
    s[t] = c;
    __syncthreads();
    for (int off = 1; off < 256; off <<= 1) {
        int x = (t >= off) ? s[t - off] : 0;
        __syncthreads();
        s[t] += x;
        __syncthreads();
    }
    if (t < NBLK) psum[t] = s[t] - c;
}

__global__ __launch_bounds__(256) void scan3_kernel(
    const int* __restrict__ rp1loc, const int* __restrict__ psum,
    int* __restrict__ rowptr, int* __restrict__ cursor, int N)
{
    int t = blockIdx.x * 256 + threadIdx.x;
    int T = gridDim.x * 256;
    for (int i = t; i < N; i += T) {
        rowptr[i + 1] = rp1loc[i] + psum[i >> 10];
        cursor[i] = (i == 0) ? 0 : rp1loc[i - 1] + psum[(i - 1) >> 10];
    }
    if (t == 0) rowptr[0] = 0;
}

__global__ __launch_bounds__(256) void scatter_kernel(
    const int* __restrict__ ei, int* __restrict__ cursor,
    int* __restrict__ col, int E)
{
    int t = blockIdx.x * 256 + threadIdx.x;
    int T = gridDim.x * 256;
    for (int e = t; e < E; e += T) {
        int d = ei[E + e];
        int pos = atomicAdd(&cursor[d], 1);
        col[pos] = ei[e];
    }
}

// ---------------------------------------------------------------------------
// Aggregation (v8, at its per-CU miss-concurrency limit ~103us; unchanged).
// ---------------------------------------------------------------------------
__global__ __launch_bounds__(256) void agg_kernel(
    const int* __restrict__ rowptr, const int* __restrict__ col,
    const float* __restrict__ Y2, const unsigned* __restrict__ QV,
    const int* __restrict__ batch,
    float* __restrict__ H, float* __restrict__ stats,
    float* __restrict__ gsumy, int N)
{
    const int tid = threadIdx.x;
    const int lane = tid & 63;
    const int wid = __builtin_amdgcn_readfirstlane(
        (int)((blockIdx.x * blockDim.x + tid) >> 6));
    const int NW = (gridDim.x * blockDim.x) >> 6;
    const int chunk = (N + NW - 1) / NW;
    const int nA = wid * chunk;
    const int nB = min(N, nA + chunk);
    const float L2E = 1.44269504f;

    float st1 = 0.0f, st2 = 0.0f, gacc = 0.0f;
    int cur = -1;

    if (nA < nB) {
        int n = nA;
        int e = __builtin_amdgcn_readfirstlane(rowptr[nA]);
        const int eB = __builtin_amdgcn_readfirstlane(rowptr[nB]);
        int r1 = __builtin_amdgcn_readfirstlane(rowptr[nA + 1]);
        float acc = Y2[(size_t)n * 128 + 64 + lane];
        float nkl = Y2[(size_t)n * 128 + lane] * (-L2E);

        auto finishAdvance = [&]() {
            float y = __builtin_amdgcn_rcpf(
                1.0f + __builtin_amdgcn_exp2f(acc * (-L2E)));
            H[(size_t)n * 64 + lane] = y;
            st1 += y;
            st2 += y * y;
            int gi = __builtin_amdgcn_readfirstlane(batch[n]);
            if (gi != cur) {
                if (cur >= 0) atomicAdd(&gsumy[cur * 64 + lane], gacc);
                gacc = 0.0f;
                cur = gi;
            }
            gacc += y;
            ++n;
            if (n < nB) {
                r1 = __builtin_amdgcn_readfirstlane(rowptr[n + 1]);
                acc = Y2[(size_t)n * 128 + 64 + lane];
                nkl = Y2[(size_t)n * 128 + lane] * (-L2E);
            }
        };

#define RFL_(v, i) int v = __builtin_amdgcn_readfirstlane(col[e + i]);
#define GATH_(u, v) unsigned u = QV[((size_t)v << 6) + lane];
#define EDGE_(u, i)                                                          \
    {                                                                        \
        while (e + i == r1) finishAdvance();                                 \
        unsigned uu_ = u;                                                    \
        float2 f_ = __half22float2(*reinterpret_cast<__half2*>(&uu_));       \
        float ex_ = __builtin_amdgcn_exp2f(fmaf(f_.x, -L2E, nkl));           \
        acc = fmaf(__builtin_amdgcn_rcpf(1.0f + ex_), f_.y, acc);            \
    }

        while (e + 16 <= eB) {
            RFL_(sa_, 0)  RFL_(sb_, 1)  RFL_(sc_, 2)  RFL_(sd_, 3)
            RFL_(se_, 4)  RFL_(sf_, 5)  RFL_(sg_, 6)  RFL_(sh_, 7)
            RFL_(si_, 8)  RFL_(sj_, 9)  RFL_(sk_, 10) RFL_(sl_, 11)
            RFL_(sm_, 12) RFL_(sn_, 13) RFL_(so_, 14) RFL_(sp_, 15)
            GATH_(ua_, sa_) GATH_(ub_, sb_) GATH_(uc_, sc_) GATH_(ud_, sd_)
            GATH_(ue_, se_) GATH_(uf_, sf_) GATH_(ug_, sg_) GATH_(uh_, sh_)
            GATH_(ui_, si_) GATH_(uj_, sj_) GATH_(uk_, sk_) GATH_(ul_, sl_)
            GATH_(um_, sm_) GATH_(un_, sn_) GATH_(uo_, so_) GATH_(up_, sp_)
            EDGE_(ua_, 0)  EDGE_(ub_, 1)  EDGE_(uc_, 2)  EDGE_(ud_, 3)
            EDGE_(ue_, 4)  EDGE_(uf_, 5)  EDGE_(ug_, 6)  EDGE_(uh_, 7)
            EDGE_(ui_, 8)  EDGE_(uj_, 9)  EDGE_(uk_, 10) EDGE_(ul_, 11)
            EDGE_(um_, 12) EDGE_(un_, 13) EDGE_(uo_, 14) EDGE_(up_, 15)
            e += 16;
        }
        for (; e < eB; ++e) {
            while (e == r1) finishAdvance();
            int sx_ = __builtin_amdgcn_readfirstlane(col[e]);
            unsigned ux_ = QV[((size_t)sx_ << 6) + lane];
            float2 f_ = __half22float2(*reinterpret_cast<__half2*>(&ux_));
            float ex_ = __builtin_amdgcn_exp2f(fmaf(f_.x, -L2E, nkl));
            acc = fmaf(__builtin_amdgcn_rcpf(1.0f + ex_), f_.y, acc);
        }
        while (n < nB) finishAdvance();
#undef RFL_
#undef GATH_
#undef EDGE_
    }
    if (cur >= 0) atomicAdd(&gsumy[cur * 64 + lane], gacc);

    __shared__ float red1[4][64], red2[4][64];
    const int w = tid >> 6;
    red1[w][lane] = st1;
    red2[w][lane] = st2;
    __syncthreads();
    if (tid < 64) {
        float a = red1[0][lane] + red1[1][lane] + red1[2][lane] + red1[3][lane];
        float c = red2[0][lane] + red2[1][lane] + red2[2][lane] + red2[3][lane];
        atomicAdd(&stats[lane], a);
        atomicAdd(&stats[64 + lane], c);
    }
}

// ---------------------------------------------------------------------------
// Head kernels (unchanged).
// ---------------------------------------------------------------------------
__global__ __launch_bounds__(128) void head1_kernel(
    const float* __restrict__ gsumy0, const float* __restrict__ gsumy1,
    const float* __restrict__ counts,
    const float* __restrict__ stats0, const float* __restrict__ stats1,
    const float* __restrict__ g0, const float* __restrict__ be0,
    const float* __restrict__ g1, const float* __restrict__ be1,
    const float* __restrict__ Wh0, const float* __restrict__ bh0,
    float* __restrict__ t0, float* __restrict__ hstat0, float invN)
{
    const int gr = blockIdx.x;
    const int o = threadIdx.x;
    __shared__ float feat[256];

    const float* st = (o < 64) ? stats0 : stats1;
    const float* gg = (o < 64) ? g0 : g1;
    const float* bb = (o < 64) ? be0 : be1;
    const float* gs = (o < 64) ? gsumy0 : gsumy1;
    int c = o & 63;
    float m = st[c] * invN;
    float var = st[64 + c] * invN - m * m;
    float rs = rsqrtf(var + EPS) * gg[c];
    float off = bb[c] - m * rs;
    float cnt = counts[gr];
    float sv = rs * gs[gr * 64 + c] + cnt * off;
    float inv = __fdividef(1.0f, fmaxf(cnt, 1.0f));
    feat[o] = sv * inv;
    feat[128 + o] = sv;
    __syncthreads();

    float acc = bh0[o];
    for (int j = 0; j < 256; ++j) acc = fmaf(feat[j], Wh0[j * 128 + o], acc);
    float y = sigmoidf_(acc);
    t0[gr * 128 + o] = y;
    atomicAdd(&hstat0[o], y);
    atomicAdd(&hstat0[128 + o], y * y);
}

__global__ __launch_bounds__(64) void head2_kernel(
    const float* __restrict__ t0, const float* __restrict__ hstat0,
    const float* __restrict__ gh0, const float* __restrict__ beh0,
    const float* __restrict__ Wh1, const float* __restrict__ bh1,
    float* __restrict__ t1, float* __restrict__ hstat1)
{
    const int gr = blockIdx.x;
    const int o = threadIdx.x;
    __shared__ float bn0[128];
    const float invG = 1.0f / (float)N_GRAPHS;
    for (int j = o; j < 128; j += 64) {
        float m = hstat0[j] * invG;
        float v = hstat0[128 + j] * invG - m * m;
        bn0[j] = (t0[gr * 128 + j] - m) * rsqrtf(v + EPS) * gh0[j] + beh0[j];
    }
    __syncthreads();
    float acc = bh1[o];
    for (int j = 0; j < 128; ++j) acc = fmaf(bn0[j], Wh1[j * 64 + o], acc);
    float y = sigmoidf_(acc);
    t1[gr * 64 + o] = y;
    atomicAdd(&hstat1[o], y);
    atomicAdd(&hstat1[64 + o], y * y);
}

__global__ __launch_bounds__(64) void head3_kernel(
    const float* __restrict__ t1, const float* __restrict__ hstat1,
    const float* __restrict__ gh1, const float* __restrict__ beh1,
    const float* __restrict__ Wc, const float* __restrict__ bc,
    float* __restrict__ out)
{
    const int gr = blockIdx.x;
    const int o = threadIdx.x;
    const float invG = 1.0f / (float)N_GRAPHS;
    float m = hstat1[o] * invG;
    float v = hstat1[64 + o] * invG - m * m;
    float b = (t1[gr * 64 + o] - m) * rsqrtf(v + EPS) * gh1[o] + beh1[o];
    float p0 = b * Wc[o * 2];
    float p1 = b * Wc[o * 2 + 1];
#pragma unroll
    for (int off = 32; off > 0; off >>= 1) {
        p0 += __shfl_down(p0, off);
        p1 += __shfl_down(p1, off);
    }
    if (o == 0) {
        out[gr * 2] = p0 + bc[0];
        out[gr * 2 + 1] = p1 + bc[1];
    }
}

// ---------------------------------------------------------------------------
extern "C" void kernel_launch(void* const* d_in, const int* in_sizes, int n_in,
                              void* d_out, int out_size, void* d_ws, size_t ws_size,
                              hipStream_t stream)
{
    const float* x     = (const float*)d_in[0];
    const int*   ei    = (const int*)d_in[1];
    const int*   batch = (const int*)d_in[2];
    const int N = in_sizes[2];
    const int E = in_sizes[1] / 2;
    const int NCHUNK = (N + 1023) / 1024;

    const float *Wk0 = (const float*)d_in[3],  *bk0 = (const float*)d_in[4];
    const float *Wq0 = (const float*)d_in[5],  *bq0 = (const float*)d_in[6];
    const float *Wv0 = (const float*)d_in[7],  *bv0 = (const float*)d_in[8];
    const float *Ws0 = (const float*)d_in[9],  *cb0 = (const float*)d_in[10];
    const float *g0  = (const float*)d_in[11], *be0 = (const float*)d_in[12];
    const float *Wk1 = (const float*)d_in[13], *bk1 = (const float*)d_in[14];
    const float *Wq1 = (const float*)d_in[15], *bq1 = (const float*)d_in[16];
    const float *Wv1 = (const float*)d_in[17], *bv1 = (const float*)d_in[18];
    const float *Ws1 = (const float*)d_in[19], *cb1 = (const float*)d_in[20];
    const float *g1  = (const float*)d_in[21], *be1 = (const float*)d_in[22];
    const float *Wh0 = (const float*)d_in[23], *bh0 = (const float*)d_in[24];
    const float *gh0 = (const float*)d_in[25], *beh0 = (const float*)d_in[26];
    const float *Wh1 = (const float*)d_in[27], *bh1 = (const float*)d_in[28];
    const float *gh1 = (const float*)d_in[29], *beh1 = (const float*)d_in[30];
    const float *Wc  = (const float*)d_in[31], *bc  = (const float*)d_in[32];

    float*    ws = (float*)d_ws;
    float*    Y2 = ws;                          // N*128 fp32 [k|s]
    unsigned* QV = (unsigned*)(Y2 + (size_t)N * 128);  // N*64 packed fp16 q|v
    float*    H  = (float*)(QV + (size_t)N * 64);      // N*64 fp32 (raw y)
    int*   col     = (int*)(H + (size_t)N * 64);       // E
    int*   rowptr  = col + E;             // N+1
    int*   rp1loc  = rowptr + N + 1;      // N
    int*   cursor  = rp1loc + N;          // N
    int*   psum    = cursor + N;          // 256
    uintptr_t pAl = ((uintptr_t)(psum + 256) + 63) & ~(uintptr_t)63;
    short* BT0h = (short*)pAl;            // 256*128 bf16 hi
    short* BT0l = BT0h + 256 * 128;       // 256*128 bf16 lo
    float* bf0  = (float*)(BT0l + 256 * 128);  // 256
    short* BT1h = (short*)(bf0 + 256);    // 256*64 bf16 hi
    short* BT1l = BT1h + 256 * 64;        // 256*64 bf16 lo
    float* bf1  = (float*)(BT1l + 256 * 64);   // 256
    int*   deg     = (int*)(bf1 + 256);   // N    <-- zero zone starts here
    float* gsumy0 = (float*)(deg + N);    // 128*64
    float* gsumy1 = gsumy0 + 128 * 64;    // 128*64
    float* counts = gsumy1 + 128 * 64;    // 128
    float* stats0 = counts + 128;         // 128
    float* stats1 = stats0 + 128;         // 128
    float* hstat0 = stats1 + 128;         // 256
    float* hstat1 = hstat0 + 256;         // 128
    size_t zbytes = (size_t)N * sizeof(int) +
                    (size_t)(128 * 64 * 2 + 128 * 3 + 256 + 128) * sizeof(float);
    float* t0 = hstat1 + 128;             // 128*128
    float* t1 = t0 + 128 * 128;           // 128*64

    hipMemsetAsync(deg, 0, zbytes, stream);

    // ---- fused prep (deg + counts + split-bf16 weight fusion) ----
    prep_kernel<<<400, 256, 0, stream>>>(
        ei, deg, E, batch, counts, N,
        Wk0, bk0, Wq0, bq0, Wv0, bv0, Ws0, cb0, BT0h, BT0l, bf0,
        Wk1, bk1, Wq1, bq1, Wv1, bv1, Ws1, cb1, BT1h, BT1l, bf1);
    scan1_kernel<<<NCHUNK, 256, 0, stream>>>(deg, rp1loc, psum, N);
    scan2_kernel<<<1, 256, 0, stream>>>(psum, NCHUNK);
    scan3_kernel<<<256, 256, 0, stream>>>(rp1loc, psum, rowptr, cursor, N);
    scatter_kernel<<<512, 256, 0, stream>>>(ei, cursor, col, E);

    const float invN = 1.0f / (float)N;
    const int projBlocks = (N + 63) / 64;

    // ---- layer 0 ----
    proj_mfma_kernel<128, false><<<projBlocks, 256, 0, stream>>>(
        x, BT0h, BT0l, bf0, nullptr, nullptr, nullptr, invN, Y2, QV, N);
    agg_kernel<<<2048, 256, 0, stream>>>(rowptr, col, Y2, QV, batch,
                                         H, stats0, gsumy0, N);

    // ---- layer 1 (BN affine computed in-kernel from stats0) ----
    proj_mfma_kernel<64, true><<<projBlocks, 256, 0, stream>>>(
        H, BT1h, BT1l, bf1, stats0, g0, be0, invN, Y2, QV, N);
    agg_kernel<<<2048, 256, 0, stream>>>(rowptr, col, Y2, QV, batch,
                                         H, stats1, gsumy1, N);

    // ---- head ----
    head1_kernel<<<128, 128, 0, stream>>>(gsumy0, gsumy1, counts,
                                          stats0, stats1, g0, be0, g1, be1,
                                          Wh0, bh0, t0, hstat0, invN);
    head2_kernel<<<128, 64, 0, stream>>>(t0, hstat0, gh0, beh0, Wh1, bh1, t1, hstat1);
    head3_kernel<<<128, 64, 0, stream>>>(t1, hstat1, gh1, beh1, Wc, bc, (float*)d_out);
}

// Round 4
// 517.929 us; speedup vs baseline: 1.2568x; 1.1227x over previous
//
#include <hip/hip_runtime.h>
#include <hip/hip_fp16.h>
#include <math.h>

#define EPS 1e-5f
#define N_GRAPHS 128

typedef __attribute__((ext_vector_type(8))) short s8v;
typedef __attribute__((ext_vector_type(4))) float f4v;

__device__ __forceinline__ float sigmoidf_(float x) {
    return __fdividef(1.0f, 1.0f + __expf(-x));
}

__device__ __forceinline__ short bf16rne(float f) {
    unsigned u = __builtin_bit_cast(unsigned, f);
    unsigned r = (u + 0x7FFFu + ((u >> 16) & 1u)) >> 16;
    return (short)r;
}
__device__ __forceinline__ float bf16tof(short h) {
    unsigned u = ((unsigned)(unsigned short)h) << 16;
    return __builtin_bit_cast(float, u);
}

// ---------------------------------------------------------------------------
// Fused prep: block-range partition.
//  [0,256):  deg histogram + per-edge slot capture (pos_)
//  [256,320): fuse_w layer0 (K=128)   [320,384): fuse_w layer1 (K=64)
//  [384,400): per-graph counts
// Weights fused (cols: [0,64)=Wk, [64,128)=Ws, [128,256)=interleaved (Wq,Wv)
// pairs), transposed to [col][k], SPLIT into hi/lo bf16 (3-product split-bf16
// MFMA reproduces fp32 accuracy).
// ---------------------------------------------------------------------------
__device__ __forceinline__ void fuse_w_body(
    int b0, int blk, int tid,
    const float* __restrict__ Wk, const float* __restrict__ bk,
    const float* __restrict__ Wq, const float* __restrict__ bq,
    const float* __restrict__ Wv, const float* __restrict__ bv,
    const float* __restrict__ Ws, const float* __restrict__ cbv,
    short* __restrict__ BTh, short* __restrict__ BTl,
    float* __restrict__ bf, int K)
{
    int t = (blk - b0) * 256 + tid;
    int total = K * 256;
    for (int i = t; i < total; i += 64 * 256) {
        int k = i >> 8, c = i & 255;
        const float* W;
        int cc;
        if (c < 64)       { W = Wk; cc = c; }
        else if (c < 128) { W = Ws; cc = c - 64; }
        else { int j = c - 128; cc = j >> 1; W = (j & 1) ? Wv : Wq; }
        float wv = W[k * 64 + cc];
        short h = bf16rne(wv);
        short l = bf16rne(wv - bf16tof(h));
        BTh[(size_t)c * K + k] = h;
        BTl[(size_t)c * K + k] = l;
    }
    if (t < 256) {
        int c = t;
        const float* b;
        int cc;
        if (c < 64)       { b = bk;  cc = c; }
        else if (c < 128) { b = cbv; cc = c - 64; }
        else { int j = c - 128; cc = j >> 1; b = (j & 1) ? bv : bq; }
        bf[t] = b[cc];
    }
}

__global__ __launch_bounds__(256) void prep_kernel(
    const int* __restrict__ ei, int* __restrict__ deg,
    int* __restrict__ pos_, int E,
    const int* __restrict__ batch, float* __restrict__ counts, int N,
    const float* __restrict__ Wk0, const float* __restrict__ bk0,
    const float* __restrict__ Wq0, const float* __restrict__ bq0,
    const float* __restrict__ Wv0, const float* __restrict__ bv0,
    const float* __restrict__ Ws0, const float* __restrict__ cb0,
    short* __restrict__ BT0h, short* __restrict__ BT0l, float* __restrict__ bf0,
    const float* __restrict__ Wk1, const float* __restrict__ bk1,
    const float* __restrict__ Wq1, const float* __restrict__ bq1,
    const float* __restrict__ Wv1, const float* __restrict__ bv1,
    const float* __restrict__ Ws1, const float* __restrict__ cb1,
    short* __restrict__ BT1h, short* __restrict__ BT1l, float* __restrict__ bf1)
{
    const int blk = blockIdx.x;
    const int tid = threadIdx.x;
    if (blk < 256) {
        int t = blk * 256 + tid;
        for (int e = t; e < E; e += 256 * 256) {
            // same atomic as before, but capture the slot -> scatter needs
            // no atomics (removes its dependent atomic->store chain)
            pos_[e] = atomicAdd(&deg[ei[E + e]], 1);
        }
    } else if (blk < 320) {
        fuse_w_body(256, blk, tid, Wk0, bk0, Wq0, bq0, Wv0, bv0, Ws0, cb0,
                    BT0h, BT0l, bf0, 128);
    } else if (blk < 384) {
        fuse_w_body(320, blk, tid, Wk1, bk1, Wq1, bq1, Wv1, bv1, Ws1, cb1,
                    BT1h, BT1l, bf1, 64);
    } else {
        const int t = (blk - 384) * 256 + tid;
        const int T = 16 * 256;
        const int chunk = (N + T - 1) / T;
        const int a = t * chunk;
        const int b = min(N, a + chunk);
        int cur = -1;
        float c = 0.0f;
        for (int n = a; n < b; ++n) {
            int gi = batch[n];
            if (gi != cur) {
                if (cur >= 0) atomicAdd(&counts[cur], c);
                cur = gi;
                c = 0.0f;
            }
            c += 1.0f;
        }
        if (cur >= 0) atomicAdd(&counts[cur], c);
    }
}

// ---------------------------------------------------------------------------
// Projection: split-bf16 MFMA GEMM (AhBh + AhBl + AlBh, fp32 accumulate).
// Tile M=64 x N=256 fused cols; 4 waves each own 64 cols x 64 rows.
// ---------------------------------------------------------------------------
template <int K, bool AFF>
__global__ __launch_bounds__(256) void proj_mfma_kernel(
    const float* __restrict__ X,
    const short* __restrict__ BTh, const short* __restrict__ BTl,
    const float* __restrict__ bf,
    const float* __restrict__ stats, const float* __restrict__ g,
    const float* __restrict__ be, float invN,
    float* __restrict__ Y2, unsigned* __restrict__ QV, int N)
{
    __shared__ __attribute__((aligned(16))) short Ah_s[64 * 40];
    __shared__ __attribute__((aligned(16))) short Al_s[64 * 40];
    const int tid = threadIdx.x;
    const int lane = tid & 63;
    const int w = tid >> 6;
    const int n0 = blockIdx.x * 64;
    const int m = lane & 15;
    const int kg = lane >> 4;
    const int srow = tid >> 2;
    const int skq = (tid & 3) * 8;

    f4v acc[4][4];
#pragma unroll
    for (int rb = 0; rb < 4; ++rb)
#pragma unroll
        for (int cc = 0; cc < 4; ++cc) {
            acc[rb][cc][0] = 0.0f; acc[rb][cc][1] = 0.0f;
            acc[rb][cc][2] = 0.0f; acc[rb][cc][3] = 0.0f;
        }

    for (int k0 = 0; k0 < K; k0 += 32) {
        s8v Bh[4], Bl[4];
#pragma unroll
        for (int cc = 0; cc < 4; ++cc) {
            const int colb = (w * 4 + cc) * 16 + m;
            const size_t off = (size_t)colb * K + k0 + kg * 8;
            Bh[cc] = *(const s8v*)&BTh[off];
            Bl[cc] = *(const s8v*)&BTl[off];
        }
        __syncthreads();
        {
            float xv[8];
            const int row = n0 + srow;
            if (row < N) {
                float4 x0 = *(const float4*)&X[(size_t)row * K + k0 + skq];
                float4 x1 = *(const float4*)&X[(size_t)row * K + k0 + skq + 4];
                xv[0] = x0.x; xv[1] = x0.y; xv[2] = x0.z; xv[3] = x0.w;
                xv[4] = x1.x; xv[5] = x1.y; xv[6] = x1.z; xv[7] = x1.w;
            } else {
#pragma unroll
                for (int i = 0; i < 8; ++i) xv[i] = 0.0f;
            }
            if constexpr (AFF) {
#pragma unroll
                for (int i = 0; i < 8; ++i) {
                    int c = k0 + skq + i;
                    float mm = stats[c] * invN;
                    float vv = stats[64 + c] * invN - mm * mm;
                    float rs = rsqrtf(vv + EPS) * g[c];
                    xv[i] = fmaf(xv[i], rs, be[c] - mm * rs);
                }
            }
            s8v vh, vl;
#pragma unroll
            for (int i = 0; i < 8; ++i) {
                short h = bf16rne(xv[i]);
                vh[i] = h;
                vl[i] = bf16rne(xv[i] - bf16tof(h));
            }
            *(s8v*)&Ah_s[srow * 40 + skq] = vh;
            *(s8v*)&Al_s[srow * 40 + skq] = vl;
        }
        __syncthreads();
#pragma unroll
        for (int rb = 0; rb < 4; ++rb) {
            const int aoff = (rb * 16 + m) * 40 + kg * 8;
            s8v Ah = *(const s8v*)&Ah_s[aoff];
            s8v Al = *(const s8v*)&Al_s[aoff];
#pragma unroll
            for (int cc = 0; cc < 4; ++cc) {
                acc[rb][cc] = __builtin_amdgcn_mfma_f32_16x16x32_bf16(
                    Ah, Bh[cc], acc[rb][cc], 0, 0, 0);
                acc[rb][cc] = __builtin_amdgcn_mfma_f32_16x16x32_bf16(
                    Ah, Bl[cc], acc[rb][cc], 0, 0, 0);
                acc[rb][cc] = __builtin_amdgcn_mfma_f32_16x16x32_bf16(
                    Al, Bh[cc], acc[rb][cc], 0, 0, 0);
            }
        }
    }

#pragma unroll
    for (int rb = 0; rb < 4; ++rb) {
#pragma unroll
        for (int cc = 0; cc < 4; ++cc) {
            const int colb = (w * 4 + cc) * 16 + m;
            const float bias = bf[colb];
#pragma unroll
            for (int j = 0; j < 4; ++j) {
                const int row = n0 + rb * 16 + kg * 4 + j;
                float val = acc[rb][cc][j] + bias;
                if (w < 2) {
                    if (row < N) Y2[(size_t)row * 128 + colb] = val;
                } else {
                    float pv = __shfl_xor(val, 1);
                    if (!(lane & 1) && row < N) {
                        __half2 h2 = __floats2half2_rn(val, pv);
                        QV[(size_t)row * 64 + ((colb - 128) >> 1)] =
                            *reinterpret_cast<unsigned*>(&h2);
                    }
                }
            }
        }
    }
}

// ---------------------------------------------------------------------------
// CSR scans + atomic-free scatter.
// ---------------------------------------------------------------------------
__global__ __launch_bounds__(256) void scan1_kernel(
    const int* __restrict__ deg, int* __restrict__ rp1loc,
    int* __restrict__ psum, int N)
{
    __shared__ int s[256];
    const int b = blockIdx.x;
    const int base = b * 1024;
    const int t = threadIdx.x;
    int v[4], sum = 0;
#pragma unroll
    for (int i = 0; i < 4; ++i) {
        int idx = base + t * 4 + i;
        v[i] = (idx < N) ? deg[idx] : 0;
        sum += v[i];
    }
    s[t] = sum;
    __syncthreads();
    for (int off = 1; off < 256; off <<= 1) {
        int x = (t >= off) ? s[t - off] : 0;
        __syncthreads();
        s[t] += x;
        __syncthreads();
    }
    int run = s[t] - sum;
#pragma unroll
    for (int i = 0; i < 4; ++i) {
        run += v[i];
        int idx = base + t * 4 + i;
        if (idx < N) rp1loc[idx] = run;
    }
    if (t == 255) psum[b] = s[255];
}

__global__ __launch_bounds__(256) void scan2_kernel(int* __restrict__ psum, int NBLK)
{
    __shared__ int s[256];
    int t = threadIdx.x;
    int c = (t < NBLK) ? psum[t] : 0;
    s[t] = c;
    __syncthreads();
    for (int off = 1; off < 256; off <<= 1) {
        int x = (t >= off) ? s[t - off] : 0;
        __syncthreads();
        s[t] += x;
        __syncthreads();
    }
    if (t < NBLK) psum[t] = s[t] - c;
}

__global__ __launch_bounds__(256) void scan3_kernel(
    const int* __restrict__ rp1loc, const int* __restrict__ psum,
    int* __restrict__ rowptr, int N)
{
    int t = blockIdx.x * 256 + threadIdx.x;
    int T = gridDim.x * 256;
    for (int i = t; i < N; i += T) {
        rowptr[i + 1] = rp1loc[i] + psum[i >> 10];
    }
    if (t == 0) rowptr[0] = 0;
}

__global__ __launch_bounds__(256) void scatter_kernel(
    const int* __restrict__ ei, const int* __restrict__ rowptr,
    const int* __restrict__ pos_, int* __restrict__ col, int E)
{
    int t = blockIdx.x * 256 + threadIdx.x;
    int T = gridDim.x * 256;
    for (int e = t; e < E; e += T) {
        int d = ei[E + e];
        col[rowptr[d] + pos_[e]] = ei[e];
    }
}

// ---------------------------------------------------------------------------
// Aggregation (v8, at its per-CU miss-concurrency limit; unchanged).
// ---------------------------------------------------------------------------
__global__ __launch_bounds__(256) void agg_kernel(
    const int* __restrict__ rowptr, const int* __restrict__ col,
    const float* __restrict__ Y2, const unsigned* __restrict__ QV,
    const int* __restrict__ batch,
    float* __restrict__ H, float* __restrict__ stats,
    float* __restrict__ gsumy, int N)
{
    const int tid = threadIdx.x;
    const int lane = tid & 63;
    const int wid = __builtin_amdgcn_readfirstlane(
        (int)((blockIdx.x * blockDim.x + tid) >> 6));
    const int NW = (gridDim.x * blockDim.x) >> 6;
    const int chunk = (N + NW - 1) / NW;
    const int nA = wid * chunk;
    const int nB = min(N, nA + chunk);
    const float L2E = 1.44269504f;

    float st1 = 0.0f, st2 = 0.0f, gacc = 0.0f;
    int cur = -1;

    if (nA < nB) {
        int n = nA;
        int e = __builtin_amdgcn_readfirstlane(rowptr[nA]);
        const int eB = __builtin_amdgcn_readfirstlane(rowptr[nB]);
        int r1 = __builtin_amdgcn_readfirstlane(rowptr[nA + 1]);
        float acc = Y2[(size_t)n * 128 + 64 + lane];
        float nkl = Y2[(size_t)n * 128 + lane] * (-L2E);

        auto finishAdvance = [&]() {
            float y = __builtin_amdgcn_rcpf(
                1.0f + __builtin_amdgcn_exp2f(acc * (-L2E)));
            H[(size_t)n * 64 + lane] = y;
            st1 += y;
            st2 += y * y;
            int gi = __builtin_amdgcn_readfirstlane(batch[n]);
            if (gi != cur) {
                if (cur >= 0) atomicAdd(&gsumy[cur * 64 + lane], gacc);
                gacc = 0.0f;
                cur = gi;
            }
            gacc += y;
            ++n;
            if (n < nB) {
                r1 = __builtin_amdgcn_readfirstlane(rowptr[n + 1]);
                acc = Y2[(size_t)n * 128 + 64 + lane];
                nkl = Y2[(size_t)n * 128 + lane] * (-L2E);
            }
        };

#define RFL_(v, i) int v = __builtin_amdgcn_readfirstlane(col[e + i]);
#define GATH_(u, v) unsigned u = QV[((size_t)v << 6) + lane];
#define EDGE_(u, i)                                                          \
    {                                                                        \
        while (e + i == r1) finishAdvance();                                 \
        unsigned uu_ = u;                                                    \
        float2 f_ = __half22float2(*reinterpret_cast<__half2*>(&uu_));       \
        float ex_ = __builtin_amdgcn_exp2f(fmaf(f_.x, -L2E, nkl));           \
        acc = fmaf(__builtin_amdgcn_rcpf(1.0f + ex_), f_.y, acc);            \
    }

        while (e + 16 <= eB) {
            RFL_(sa_, 0)  RFL_(sb_, 1)  RFL_(sc_, 2)  RFL_(sd_, 3)
            RFL_(se_, 4)  RFL_(sf_, 5)  RFL_(sg_, 6)  RFL_(sh_, 7)
            RFL_(si_, 8)  RFL_(sj_, 9)  RFL_(sk_, 10) RFL_(sl_, 11)
            RFL_(sm_, 12) RFL_(sn_, 13) RFL_(so_, 14) RFL_(sp_, 15)
            GATH_(ua_, sa_) GATH_(ub_, sb_) GATH_(uc_, sc_) GATH_(ud_, sd_)
            GATH_(ue_, se_) GATH_(uf_, sf_) GATH_(ug_, sg_) GATH_(uh_, sh_)
            GATH_(ui_, si_) GATH_(uj_, sj_) GATH_(uk_, sk_) GATH_(ul_, sl_)
            GATH_(um_, sm_) GATH_(un_, sn_) GATH_(uo_, so_) GATH_(up_, sp_)
            EDGE_(ua_, 0)  EDGE_(ub_, 1)  EDGE_(uc_, 2)  EDGE_(ud_, 3)
            EDGE_(ue_, 4)  EDGE_(uf_, 5)  EDGE_(ug_, 6)  EDGE_(uh_, 7)
            EDGE_(ui_, 8)  EDGE_(uj_, 9)  EDGE_(uk_, 10) EDGE_(ul_, 11)
            EDGE_(um_, 12) EDGE_(un_, 13) EDGE_(uo_, 14) EDGE_(up_, 15)
            e += 16;
        }
        for (; e < eB; ++e) {
            while (e == r1) finishAdvance();
            int sx_ = __builtin_amdgcn_readfirstlane(col[e]);
            unsigned ux_ = QV[((size_t)sx_ << 6) + lane];
            float2 f_ = __half22float2(*reinterpret_cast<__half2*>(&ux_));
            float ex_ = __builtin_amdgcn_exp2f(fmaf(f_.x, -L2E, nkl));
            acc = fmaf(__builtin_amdgcn_rcpf(1.0f + ex_), f_.y, acc);
        }
        while (n < nB) finishAdvance();
#undef RFL_
#undef GATH_
#undef EDGE_
    }
    if (cur >= 0) atomicAdd(&gsumy[cur * 64 + lane], gacc);

    __shared__ float red1[4][64], red2[4][64];
    const int w = tid >> 6;
    red1[w][lane] = st1;
    red2[w][lane] = st2;
    __syncthreads();
    if (tid < 64) {
        float a = red1[0][lane] + red1[1][lane] + red1[2][lane] + red1[3][lane];
        float c = red2[0][lane] + red2[1][lane] + red2[2][lane] + red2[3][lane];
        atomicAdd(&stats[lane], a);
        atomicAdd(&stats[64 + lane], c);
    }
}

// ---------------------------------------------------------------------------
// Head kernels (unchanged).
// ---------------------------------------------------------------------------
__global__ __launch_bounds__(128) void head1_kernel(
    const float* __restrict__ gsumy0, const float* __restrict__ gsumy1,
    const float* __restrict__ counts,
    const float* __restrict__ stats0, const float* __restrict__ stats1,
    const float* __restrict__ g0, const float* __restrict__ be0,
    const float* __restrict__ g1, const float* __restrict__ be1,
    const float* __restrict__ Wh0, const float* __restrict__ bh0,
    float* __restrict__ t0, float* __restrict__ hstat0, float invN)
{
    const int gr = blockIdx.x;
    const int o = threadIdx.x;
    __shared__ float feat[256];

    const float* st = (o < 64) ? stats0 : stats1;
    const float* gg = (o < 64) ? g0 : g1;
    const float* bb = (o < 64) ? be0 : be1;
    const float* gs = (o < 64) ? gsumy0 : gsumy1;
    int c = o & 63;
    float m = st[c] * invN;
    float var = st[64 + c] * invN - m * m;
    float rs = rsqrtf(var + EPS) * gg[c];
    float off = bb[c] - m * rs;
    float cnt = counts[gr];
    float sv = rs * gs[gr * 64 + c] + cnt * off;
    float inv = __fdividef(1.0f, fmaxf(cnt, 1.0f));
    feat[o] = sv * inv;
    feat[128 + o] = sv;
    __syncthreads();

    float acc = bh0[o];
    for (int j = 0; j < 256; ++j) acc = fmaf(feat[j], Wh0[j * 128 + o], acc);
    float y = sigmoidf_(acc);
    t0[gr * 128 + o] = y;
    atomicAdd(&hstat0[o], y);
    atomicAdd(&hstat0[128 + o], y * y);
}

__global__ __launch_bounds__(64) void head2_kernel(
    const float* __restrict__ t0, const float* __restrict__ hstat0,
    const float* __restrict__ gh0, const float* __restrict__ beh0,
    const float* __restrict__ Wh1, const float* __restrict__ bh1,
    float* __restrict__ t1, float* __restrict__ hstat1)
{
    const int gr = blockIdx.x;
    const int o = threadIdx.x;
    __shared__ float bn0[128];
    const float invG = 1.0f / (float)N_GRAPHS;
    for (int j = o; j < 128; j += 64) {
        float m = hstat0[j] * invG;
        float v = hstat0[128 + j] * invG - m * m;
        bn0[j] = (t0[gr * 128 + j] - m) * rsqrtf(v + EPS) * gh0[j] + beh0[j];
    }
    __syncthreads();
    float acc = bh1[o];
    for (int j = 0; j < 128; ++j) acc = fmaf(bn0[j], Wh1[j * 64 + o], acc);
    float y = sigmoidf_(acc);
    t1[gr * 64 + o] = y;
    atomicAdd(&hstat1[o], y);
    atomicAdd(&hstat1[64 + o], y * y);
}

__global__ __launch_bounds__(64) void head3_kernel(
    const float* __restrict__ t1, const float* __restrict__ hstat1,
    const float* __restrict__ gh1, const float* __restrict__ beh1,
    const float* __restrict__ Wc, const float* __restrict__ bc,
    float* __restrict__ out)
{
    const int gr = blockIdx.x;
    const int o = threadIdx.x;
    const float invG = 1.0f / (float)N_GRAPHS;
    float m = hstat1[o] * invG;
    float v = hstat1[64 + o] * invG - m * m;
    float b = (t1[gr * 64 + o] - m) * rsqrtf(v + EPS) * gh1[o] + beh1[o];
    float p0 = b * Wc[o * 2];
    float p1 = b * Wc[o * 2 + 1];
#pragma unroll
    for (int off = 32; off > 0; off >>= 1) {
        p0 += __shfl_down(p0, off);
        p1 += __shfl_down(p1, off);
    }
    if (o == 0) {
        out[gr * 2] = p0 + bc[0];
        out[gr * 2 + 1] = p1 + bc[1];
    }
}

// ---------------------------------------------------------------------------
extern "C" void kernel_launch(void* const* d_in, const int* in_sizes, int n_in,
                              void* d_out, int out_size, void* d_ws, size_t ws_size,
                              hipStream_t stream)
{
    const float* x     = (const float*)d_in[0];
    const int*   ei    = (const int*)d_in[1];
    const int*   batch = (const int*)d_in[2];
    const int N = in_sizes[2];
    const int E = in_sizes[1] / 2;
    const int NCHUNK = (N + 1023) / 1024;

    const float *Wk0 = (const float*)d_in[3],  *bk0 = (const float*)d_in[4];
    const float *Wq0 = (const float*)d_in[5],  *bq0 = (const float*)d_in[6];
    const float *Wv0 = (const float*)d_in[7],  *bv0 = (const float*)d_in[8];
    const float *Ws0 = (const float*)d_in[9],  *cb0 = (const float*)d_in[10];
    const float *g0  = (const float*)d_in[11], *be0 = (const float*)d_in[12];
    const float *Wk1 = (const float*)d_in[13], *bk1 = (const float*)d_in[14];
    const float *Wq1 = (const float*)d_in[15], *bq1 = (const float*)d_in[16];
    const float *Wv1 = (const float*)d_in[17], *bv1 = (const float*)d_in[18];
    const float *Ws1 = (const float*)d_in[19], *cb1 = (const float*)d_in[20];
    const float *g1  = (const float*)d_in[21], *be1 = (const float*)d_in[22];
    const float *Wh0 = (const float*)d_in[23], *bh0 = (const float*)d_in[24];
    const float *gh0 = (const float*)d_in[25], *beh0 = (const float*)d_in[26];
    const float *Wh1 = (const float*)d_in[27], *bh1 = (const float*)d_in[28];
    const float *gh1 = (const float*)d_in[29], *beh1 = (const float*)d_in[30];
    const float *Wc  = (const float*)d_in[31], *bc  = (const float*)d_in[32];

    float*    ws = (float*)d_ws;
    float*    Y2 = ws;                          // N*128 fp32 [k|s]
    unsigned* QV = (unsigned*)(Y2 + (size_t)N * 128);  // N*64 packed fp16 q|v
    float*    H  = (float*)(QV + (size_t)N * 64);      // N*64 fp32 (raw y)
    int*   col     = (int*)(H + (size_t)N * 64);       // E
    int*   rowptr  = col + E;             // N+1
    int*   rp1loc  = rowptr + N + 1;      // N
    int*   cursor  = rp1loc + N;          // N (unused; kept for layout)
    int*   psum    = cursor + N;          // 256
    uintptr_t pAl = ((uintptr_t)(psum + 256) + 63) & ~(uintptr_t)63;
    short* BT0h = (short*)pAl;            // 256*128 bf16 hi
    short* BT0l = BT0h + 256 * 128;       // 256*128 bf16 lo
    float* bf0  = (float*)(BT0l + 256 * 128);  // 256
    short* BT1h = (short*)(bf0 + 256);    // 256*64 bf16 hi
    short* BT1l = BT1h + 256 * 64;        // 256*64 bf16 lo
    float* bf1  = (float*)(BT1l + 256 * 64);   // 256
    int*   deg     = (int*)(bf1 + 256);   // N    <-- zero zone starts here
    float* gsumy0 = (float*)(deg + N);    // 128*64
    float* gsumy1 = gsumy0 + 128 * 64;    // 128*64
    float* counts = gsumy1 + 128 * 64;    // 128
    float* stats0 = counts + 128;         // 128
    float* stats1 = stats0 + 128;         // 128
    float* hstat0 = stats1 + 128;         // 256
    float* hstat1 = hstat0 + 256;         // 128
    size_t zbytes = (size_t)N * sizeof(int) +
                    (size_t)(128 * 64 * 2 + 128 * 3 + 256 + 128) * sizeof(float);
    float* t0 = hstat1 + 128;             // 128*128
    float* t1 = t0 + 128 * 128;           // 128*64

    // pos_ aliases Y2: lifetimes are disjoint (pos_ dies at scatter,
    // Y2 is born at proj0). E ints <= N*128 floats.
    int* pos_ = (int*)Y2;

    hipMemsetAsync(deg, 0, zbytes, stream);

    // ---- fused prep (deg histogram + slot capture + counts + weights) ----
    prep_kernel<<<400, 256, 0, stream>>>(
        ei, deg, pos_, E, batch, counts, N,
        Wk0, bk0, Wq0, bq0, Wv0, bv0, Ws0, cb0, BT0h, BT0l, bf0,
        Wk1, bk1, Wq1, bq1, Wv1, bv1, Ws1, cb1, BT1h, BT1l, bf1);
    scan1_kernel<<<NCHUNK, 256, 0, stream>>>(deg, rp1loc, psum, N);
    scan2_kernel<<<1, 256, 0, stream>>>(psum, NCHUNK);
    scan3_kernel<<<256, 256, 0, stream>>>(rp1loc, psum, rowptr, N);
    scatter_kernel<<<512, 256, 0, stream>>>(ei, rowptr, pos_, col, E);

    const float invN = 1.0f / (float)N;
    const int projBlocks = (N + 63) / 64;

    // ---- layer 0 ----
    proj_mfma_kernel<128, false><<<projBlocks, 256, 0, stream>>>(
        x, BT0h, BT0l, bf0, nullptr, nullptr, nullptr, invN, Y2, QV, N);
    agg_kernel<<<2048, 256, 0, stream>>>(rowptr, col, Y2, QV, batch,
                                         H, stats0, gsumy0, N);

    // ---- layer 1 (BN affine computed in-kernel from stats0) ----
    proj_mfma_kernel<64, true><<<projBlocks, 256, 0, stream>>>(
        H, BT1h, BT1l, bf1, stats0, g0, be0, invN, Y2, QV, N);
    agg_kernel<<<2048, 256, 0, stream>>>(rowptr, col, Y2, QV, batch,
                                         H, stats1, gsumy1, N);

    // ---- head ----
    head1_kernel<<<128, 128, 0, stream>>>(gsumy0, gsumy1, counts,
                                          stats0, stats1, g0, be0, g1, be1,
                                          Wh0, bh0, t0, hstat0, invN);
    head2_kernel<<<128, 64, 0, stream>>>(t0, hstat0, gh0, beh0, Wh1, bh1, t1, hstat1);
    head3_kernel<<<128, 64, 0, stream>>>(t1, hstat1, gh1, beh1, Wc, bc, (float*)d_out);
}

// Round 5
// 488.210 us; speedup vs baseline: 1.3333x; 1.0609x over previous
//
#include <hip/hip_runtime.h>
#include <hip/hip_fp16.h>
#include <math.h>

#define EPS 1e-5f
#define N_GRAPHS 128

typedef __attribute__((ext_vector_type(8))) short s8v;
typedef __attribute__((ext_vector_type(4))) float f4v;

__device__ __forceinline__ float sigmoidf_(float x) {
    return __fdividef(1.0f, 1.0f + __expf(-x));
}

__device__ __forceinline__ short bf16rne(float f) {
    unsigned u = __builtin_bit_cast(unsigned, f);
    unsigned r = (u + 0x7FFFu + ((u >> 16) & 1u)) >> 16;
    return (short)r;
}
__device__ __forceinline__ float bf16tof(short h) {
    unsigned u = ((unsigned)(unsigned short)h) << 16;
    return __builtin_bit_cast(float, u);
}

// ---------------------------------------------------------------------------
// Fused prep: block-range partition.
//  [0,256):  deg histogram + per-edge slot capture (pos_)
//  [256,320): fuse_w layer0 (K=128)   [320,384): fuse_w layer1 (K=64)
//  [384,400): per-graph counts
// Fused weight layout (cols): [0,128) = interleaved (Wk,Ws) pairs,
// [128,256) = interleaved (Wq,Wv) pairs. Transposed to [col][k], SPLIT into
// hi/lo bf16 (3-product split-bf16 MFMA ~ fp32 accuracy). The pair
// interleave lets the proj epilogue pack (k,s) and (q,v) as fp16x2 with one
// uniform shfl_xor path.
// ---------------------------------------------------------------------------
__device__ __forceinline__ void fuse_w_body(
    int b0, int blk, int tid,
    const float* __restrict__ Wk, const float* __restrict__ bk,
    const float* __restrict__ Wq, const float* __restrict__ bq,
    const float* __restrict__ Wv, const float* __restrict__ bv,
    const float* __restrict__ Ws, const float* __restrict__ cbv,
    short* __restrict__ BTh, short* __restrict__ BTl,
    float* __restrict__ bf, int K)
{
    int t = (blk - b0) * 256 + tid;
    int total = K * 256;
    for (int i = t; i < total; i += 64 * 256) {
        int k = i >> 8, c = i & 255;
        const float* W;
        int cc;
        if (c < 128) { cc = c >> 1; W = (c & 1) ? Ws : Wk; }
        else { int j = c - 128; cc = j >> 1; W = (j & 1) ? Wv : Wq; }
        float wv = W[k * 64 + cc];
        short h = bf16rne(wv);
        short l = bf16rne(wv - bf16tof(h));
        BTh[(size_t)c * K + k] = h;
        BTl[(size_t)c * K + k] = l;
    }
    if (t < 256) {
        int c = t;
        const float* b;
        int cc;
        if (c < 128) { cc = c >> 1; b = (c & 1) ? cbv : bk; }
        else { int j = c - 128; cc = j >> 1; b = (j & 1) ? bv : bq; }
        bf[t] = b[cc];
    }
}

__global__ __launch_bounds__(256) void prep_kernel(
    const int* __restrict__ ei, int* __restrict__ deg,
    int* __restrict__ pos_, int E,
    const int* __restrict__ batch, float* __restrict__ counts, int N,
    const float* __restrict__ Wk0, const float* __restrict__ bk0,
    const float* __restrict__ Wq0, const float* __restrict__ bq0,
    const float* __restrict__ Wv0, const float* __restrict__ bv0,
    const float* __restrict__ Ws0, const float* __restrict__ cb0,
    short* __restrict__ BT0h, short* __restrict__ BT0l, float* __restrict__ bf0,
    const float* __restrict__ Wk1, const float* __restrict__ bk1,
    const float* __restrict__ Wq1, const float* __restrict__ bq1,
    const float* __restrict__ Wv1, const float* __restrict__ bv1,
    const float* __restrict__ Ws1, const float* __restrict__ cb1,
    short* __restrict__ BT1h, short* __restrict__ BT1l, float* __restrict__ bf1)
{
    const int blk = blockIdx.x;
    const int tid = threadIdx.x;
    if (blk < 256) {
        int t = blk * 256 + tid;
        for (int e = t; e < E; e += 256 * 256) {
            pos_[e] = atomicAdd(&deg[ei[E + e]], 1);
        }
    } else if (blk < 320) {
        fuse_w_body(256, blk, tid, Wk0, bk0, Wq0, bq0, Wv0, bv0, Ws0, cb0,
                    BT0h, BT0l, bf0, 128);
    } else if (blk < 384) {
        fuse_w_body(320, blk, tid, Wk1, bk1, Wq1, bq1, Wv1, bv1, Ws1, cb1,
                    BT1h, BT1l, bf1, 64);
    } else {
        const int t = (blk - 384) * 256 + tid;
        const int T = 16 * 256;
        const int chunk = (N + T - 1) / T;
        const int a = t * chunk;
        const int b = min(N, a + chunk);
        int cur = -1;
        float c = 0.0f;
        for (int n = a; n < b; ++n) {
            int gi = batch[n];
            if (gi != cur) {
                if (cur >= 0) atomicAdd(&counts[cur], c);
                cur = gi;
                c = 0.0f;
            }
            c += 1.0f;
        }
        if (cur >= 0) atomicAdd(&counts[cur], c);
    }
}

// ---------------------------------------------------------------------------
// Projection: split-bf16 MFMA GEMM (AhBh + AhBl + AlBh, fp32 accumulate).
// Tile M=64 x N=256 fused cols; 4 waves each own 64 cols x 64 rows.
// Per K-step: X-loads and B-loads issued together before ONE barrier drain
// (previously two exposed drains). Output: all fp16x2-packed pairs —
// w<2 -> KS (k,s), w>=2 -> QV (q,v). Halves write traffic vs fp32 Y2.
// ---------------------------------------------------------------------------
template <int K, bool AFF>
__global__ __launch_bounds__(256) void proj_mfma_kernel(
    const float* __restrict__ X,
    const short* __restrict__ BTh, const short* __restrict__ BTl,
    const float* __restrict__ bf,
    const float* __restrict__ stats, const float* __restrict__ g,
    const float* __restrict__ be, float invN,
    unsigned* __restrict__ KS, unsigned* __restrict__ QV, int N)
{
    __shared__ __attribute__((aligned(16))) short Ah_s[64 * 40];
    __shared__ __attribute__((aligned(16))) short Al_s[64 * 40];
    const int tid = threadIdx.x;
    const int lane = tid & 63;
    const int w = tid >> 6;
    const int n0 = blockIdx.x * 64;
    const int m = lane & 15;
    const int kg = lane >> 4;
    const int srow = tid >> 2;
    const int skq = (tid & 3) * 8;

    f4v acc[4][4];
#pragma unroll
    for (int rb = 0; rb < 4; ++rb)
#pragma unroll
        for (int cc = 0; cc < 4; ++cc) {
            acc[rb][cc][0] = 0.0f; acc[rb][cc][1] = 0.0f;
            acc[rb][cc][2] = 0.0f; acc[rb][cc][3] = 0.0f;
        }

    for (int k0 = 0; k0 < K; k0 += 32) {
        // Issue X loads first (regs), then B loads: both in flight across a
        // single barrier drain.
        float4 x0 = make_float4(0.f, 0.f, 0.f, 0.f);
        float4 x1 = make_float4(0.f, 0.f, 0.f, 0.f);
        const int row = n0 + srow;
        if (row < N) {
            x0 = *(const float4*)&X[(size_t)row * K + k0 + skq];
            x1 = *(const float4*)&X[(size_t)row * K + k0 + skq + 4];
        }
        s8v Bh[4], Bl[4];
#pragma unroll
        for (int cc = 0; cc < 4; ++cc) {
            const int colb = (w * 4 + cc) * 16 + m;
            const size_t off = (size_t)colb * K + k0 + kg * 8;
            Bh[cc] = *(const s8v*)&BTh[off];
            Bl[cc] = *(const s8v*)&BTl[off];
        }
        __syncthreads();
        {
            float xv[8] = {x0.x, x0.y, x0.z, x0.w, x1.x, x1.y, x1.z, x1.w};
            if constexpr (AFF) {
#pragma unroll
                for (int i = 0; i < 8; ++i) {
                    int c = k0 + skq + i;
                    float mm = stats[c] * invN;
                    float vv = stats[64 + c] * invN - mm * mm;
                    float rs = rsqrtf(vv + EPS) * g[c];
                    xv[i] = fmaf(xv[i], rs, be[c] - mm * rs);
                }
            }
            s8v vh, vl;
#pragma unroll
            for (int i = 0; i < 8; ++i) {
                short h = bf16rne(xv[i]);
                vh[i] = h;
                vl[i] = bf16rne(xv[i] - bf16tof(h));
            }
            *(s8v*)&Ah_s[srow * 40 + skq] = vh;
            *(s8v*)&Al_s[srow * 40 + skq] = vl;
        }
        __syncthreads();
#pragma unroll
        for (int rb = 0; rb < 4; ++rb) {
            const int aoff = (rb * 16 + m) * 40 + kg * 8;
            s8v Ah = *(const s8v*)&Ah_s[aoff];
            s8v Al = *(const s8v*)&Al_s[aoff];
#pragma unroll
            for (int cc = 0; cc < 4; ++cc) {
                acc[rb][cc] = __builtin_amdgcn_mfma_f32_16x16x32_bf16(
                    Ah, Bh[cc], acc[rb][cc], 0, 0, 0);
                acc[rb][cc] = __builtin_amdgcn_mfma_f32_16x16x32_bf16(
                    Ah, Bl[cc], acc[rb][cc], 0, 0, 0);
                acc[rb][cc] = __builtin_amdgcn_mfma_f32_16x16x32_bf16(
                    Al, Bh[cc], acc[rb][cc], 0, 0, 0);
            }
        }
    }

    // Epilogue: uniform fp16x2 pair-pack for every wave.
    unsigned* __restrict__ dst = (w < 2) ? KS : QV;
    const int cbase = (w < 2) ? 0 : 128;
#pragma unroll
    for (int rb = 0; rb < 4; ++rb) {
#pragma unroll
        for (int cc = 0; cc < 4; ++cc) {
            const int colb = (w * 4 + cc) * 16 + m;
            const float bias = bf[colb];
#pragma unroll
            for (int j = 0; j < 4; ++j) {
                const int row = n0 + rb * 16 + kg * 4 + j;
                float val = acc[rb][cc][j] + bias;
                float pv = __shfl_xor(val, 1);
                if (!(lane & 1) && row < N) {
                    __half2 h2 = __floats2half2_rn(val, pv);
                    dst[(size_t)row * 64 + ((colb - cbase) >> 1)] =
                        *reinterpret_cast<unsigned*>(&h2);
                }
            }
        }
    }
}

// ---------------------------------------------------------------------------
// CSR scans + atomic-free scatter.
// ---------------------------------------------------------------------------
__global__ __launch_bounds__(256) void scan1_kernel(
    const int* __restrict__ deg, int* __restrict__ rp1loc,
    int* __restrict__ psum, int N)
{
    __shared__ int s[256];
    const int b = blockIdx.x;
    const int base = b * 1024;
    const int t = threadIdx.x;
    int v[4], sum = 0;
#pragma unroll
    for (int i = 0; i < 4; ++i) {
        int idx = base + t * 4 + i;
        v[i] = (idx < N) ? deg[idx] : 0;
        sum += v[i];
    }
    s[t] = sum;
    __syncthreads();
    for (int off = 1; off < 256; off <<= 1) {
        int x = (t >= off) ? s[t - off] : 0;
        __syncthreads();
        s[t] += x;
        __syncthreads();
    }
    int run = s[t] - sum;
#pragma unroll
    for (int i = 0; i < 4; ++i) {
        run += v[i];
        int idx = base + t * 4 + i;
        if (idx < N) rp1loc[idx] = run;
    }
    if (t == 255) psum[b] = s[255];
}

__global__ __launch_bounds__(256) void scan2_kernel(int* __restrict__ psum, int NBLK)
{
    __shared__ int s[256];
    int t = threadIdx.x;
    int c = (t < NBLK) ? psum[t] : 0;
    s[t] = c;
    __syncthreads();
    for (int off = 1; off < 256; off <<= 1) {
        int x = (t >= off) ? s[t - off] : 0;
        __syncthreads();
        s[t] += x;
        __syncthreads();
    }
    if (t < NBLK) psum[t] = s[t] - c;
}

__global__ __launch_bounds__(256) void scan3_kernel(
    const int* __restrict__ rp1loc, const int* __restrict__ psum,
    int* __restrict__ rowptr, int N)
{
    int t = blockIdx.x * 256 + threadIdx.x;
    int T = gridDim.x * 256;
    for (int i = t; i < N; i += T) {
        rowptr[i + 1] = rp1loc[i] + psum[i >> 10];
    }
    if (t == 0) rowptr[0] = 0;
}

__global__ __launch_bounds__(256) void scatter_kernel(
    const int* __restrict__ ei, const int* __restrict__ rowptr,
    const int* __restrict__ pos_, int* __restrict__ col, int E)
{
    int t = blockIdx.x * 256 + threadIdx.x;
    int T = gridDim.x * 256;
    for (int e = t; e < E; e += T) {
        int d = ei[E + e];
        col[rowptr[d] + pos_[e]] = ei[e];
    }
}

// ---------------------------------------------------------------------------
// Aggregation: streaming edge pipeline. Per-node (k,s) now one packed fp16x2
// load from KS (was two fp32 loads from Y2).
// ---------------------------------------------------------------------------
__global__ __launch_bounds__(256) void agg_kernel(
    const int* __restrict__ rowptr, const int* __restrict__ col,
    const unsigned* __restrict__ KS, const unsigned* __restrict__ QV,
    const int* __restrict__ batch,
    float* __restrict__ H, float* __restrict__ stats,
    float* __restrict__ gsumy, int N)
{
    const int tid = threadIdx.x;
    const int lane = tid & 63;
    const int wid = __builtin_amdgcn_readfirstlane(
        (int)((blockIdx.x * blockDim.x + tid) >> 6));
    const int NW = (gridDim.x * blockDim.x) >> 6;
    const int chunk = (N + NW - 1) / NW;
    const int nA = wid * chunk;
    const int nB = min(N, nA + chunk);
    const float L2E = 1.44269504f;

    float st1 = 0.0f, st2 = 0.0f, gacc = 0.0f;
    int cur = -1;

    if (nA < nB) {
        int n = nA;
        int e = __builtin_amdgcn_readfirstlane(rowptr[nA]);
        const int eB = __builtin_amdgcn_readfirstlane(rowptr[nB]);
        int r1 = __builtin_amdgcn_readfirstlane(rowptr[nA + 1]);
        unsigned ks0 = KS[(size_t)n * 64 + lane];
        float2 kf = __half22float2(*reinterpret_cast<__half2*>(&ks0));
        float acc = kf.y;
        float nkl = kf.x * (-L2E);

        auto finishAdvance = [&]() {
            float y = __builtin_amdgcn_rcpf(
                1.0f + __builtin_amdgcn_exp2f(acc * (-L2E)));
            H[(size_t)n * 64 + lane] = y;
            st1 += y;
            st2 += y * y;
            int gi = __builtin_amdgcn_readfirstlane(batch[n]);
            if (gi != cur) {
                if (cur >= 0) atomicAdd(&gsumy[cur * 64 + lane], gacc);
                gacc = 0.0f;
                cur = gi;
            }
            gacc += y;
            ++n;
            if (n < nB) {
                r1 = __builtin_amdgcn_readfirstlane(rowptr[n + 1]);
                unsigned ks1 = KS[(size_t)n * 64 + lane];
                float2 kf1 = __half22float2(*reinterpret_cast<__half2*>(&ks1));
                acc = kf1.y;
                nkl = kf1.x * (-L2E);
            }
        };

#define RFL_(v, i) int v = __builtin_amdgcn_readfirstlane(col[e + i]);
#define GATH_(u, v) unsigned u = QV[((size_t)v << 6) + lane];
#define EDGE_(u, i)                                                          \
    {                                                                        \
        while (e + i == r1) finishAdvance();                                 \
        unsigned uu_ = u;                                                    \
        float2 f_ = __half22float2(*reinterpret_cast<__half2*>(&uu_));       \
        float ex_ = __builtin_amdgcn_exp2f(fmaf(f_.x, -L2E, nkl));           \
        acc = fmaf(__builtin_amdgcn_rcpf(1.0f + ex_), f_.y, acc);            \
    }

        while (e + 16 <= eB) {
            RFL_(sa_, 0)  RFL_(sb_, 1)  RFL_(sc_, 2)  RFL_(sd_, 3)
            RFL_(se_, 4)  RFL_(sf_, 5)  RFL_(sg_, 6)  RFL_(sh_, 7)
            RFL_(si_, 8)  RFL_(sj_, 9)  RFL_(sk_, 10) RFL_(sl_, 11)
            RFL_(sm_, 12) RFL_(sn_, 13) RFL_(so_, 14) RFL_(sp_, 15)
            GATH_(ua_, sa_) GATH_(ub_, sb_) GATH_(uc_, sc_) GATH_(ud_, sd_)
            GATH_(ue_, se_) GATH_(uf_, sf_) GATH_(ug_, sg_) GATH_(uh_, sh_)
            GATH_(ui_, si_) GATH_(uj_, sj_) GATH_(uk_, sk_) GATH_(ul_, sl_)
            GATH_(um_, sm_) GATH_(un_, sn_) GATH_(uo_, so_) GATH_(up_, sp_)
            EDGE_(ua_, 0)  EDGE_(ub_, 1)  EDGE_(uc_, 2)  EDGE_(ud_, 3)
            EDGE_(ue_, 4)  EDGE_(uf_, 5)  EDGE_(ug_, 6)  EDGE_(uh_, 7)
            EDGE_(ui_, 8)  EDGE_(uj_, 9)  EDGE_(uk_, 10) EDGE_(ul_, 11)
            EDGE_(um_, 12) EDGE_(un_, 13) EDGE_(uo_, 14) EDGE_(up_, 15)
            e += 16;
        }
        for (; e < eB; ++e) {
            while (e == r1) finishAdvance();
            int sx_ = __builtin_amdgcn_readfirstlane(col[e]);
            unsigned ux_ = QV[((size_t)sx_ << 6) + lane];
            float2 f_ = __half22float2(*reinterpret_cast<__half2*>(&ux_));
            float ex_ = __builtin_amdgcn_exp2f(fmaf(f_.x, -L2E, nkl));
            acc = fmaf(__builtin_amdgcn_rcpf(1.0f + ex_), f_.y, acc);
        }
        while (n < nB) finishAdvance();
#undef RFL_
#undef GATH_
#undef EDGE_
    }
    if (cur >= 0) atomicAdd(&gsumy[cur * 64 + lane], gacc);

    __shared__ float red1[4][64], red2[4][64];
    const int w = tid >> 6;
    red1[w][lane] = st1;
    red2[w][lane] = st2;
    __syncthreads();
    if (tid < 64) {
        float a = red1[0][lane] + red1[1][lane] + red1[2][lane] + red1[3][lane];
        float c = red2[0][lane] + red2[1][lane] + red2[2][lane] + red2[3][lane];
        atomicAdd(&stats[lane], a);
        atomicAdd(&stats[64 + lane], c);
    }
}

// ---------------------------------------------------------------------------
// Head kernels (unchanged).
// ---------------------------------------------------------------------------
__global__ __launch_bounds__(128) void head1_kernel(
    const float* __restrict__ gsumy0, const float* __restrict__ gsumy1,
    const float* __restrict__ counts,
    const float* __restrict__ stats0, const float* __restrict__ stats1,
    const float* __restrict__ g0, const float* __restrict__ be0,
    const float* __restrict__ g1, const float* __restrict__ be1,
    const float* __restrict__ Wh0, const float* __restrict__ bh0,
    float* __restrict__ t0, float* __restrict__ hstat0, float invN)
{
    const int gr = blockIdx.x;
    const int o = threadIdx.x;
    __shared__ float feat[256];

    const float* st = (o < 64) ? stats0 : stats1;
    const float* gg = (o < 64) ? g0 : g1;
    const float* bb = (o < 64) ? be0 : be1;
    const float* gs = (o < 64) ? gsumy0 : gsumy1;
    int c = o & 63;
    float m = st[c] * invN;
    float var = st[64 + c] * invN - m * m;
    float rs = rsqrtf(var + EPS) * gg[c];
    float off = bb[c] - m * rs;
    float cnt = counts[gr];
    float sv = rs * gs[gr * 64 + c] + cnt * off;
    float inv = __fdividef(1.0f, fmaxf(cnt, 1.0f));
    feat[o] = sv * inv;
    feat[128 + o] = sv;
    __syncthreads();

    float acc = bh0[o];
    for (int j = 0; j < 256; ++j) acc = fmaf(feat[j], Wh0[j * 128 + o], acc);
    float y = sigmoidf_(acc);
    t0[gr * 128 + o] = y;
    atomicAdd(&hstat0[o], y);
    atomicAdd(&hstat0[128 + o], y * y);
}

__global__ __launch_bounds__(64) void head2_kernel(
    const float* __restrict__ t0, const float* __restrict__ hstat0,
    const float* __restrict__ gh0, const float* __restrict__ beh0,
    const float* __restrict__ Wh1, const float* __restrict__ bh1,
    float* __restrict__ t1, float* __restrict__ hstat1)
{
    const int gr = blockIdx.x;
    const int o = threadIdx.x;
    __shared__ float bn0[128];
    const float invG = 1.0f / (float)N_GRAPHS;
    for (int j = o; j < 128; j += 64) {
        float m = hstat0[j] * invG;
        float v = hstat0[128 + j] * invG - m * m;
        bn0[j] = (t0[gr * 128 + j] - m) * rsqrtf(v + EPS) * gh0[j] + beh0[j];
    }
    __syncthreads();
    float acc = bh1[o];
    for (int j = 0; j < 128; ++j) acc = fmaf(bn0[j], Wh1[j * 64 + o], acc);
    float y = sigmoidf_(acc);
    t1[gr * 64 + o] = y;
    atomicAdd(&hstat1[o], y);
    atomicAdd(&hstat1[64 + o], y * y);
}

__global__ __launch_bounds__(64) void head3_kernel(
    const float* __restrict__ t1, const float* __restrict__ hstat1,
    const float* __restrict__ gh1, const float* __restrict__ beh1,
    const float* __restrict__ Wc, const float* __restrict__ bc,
    float* __restrict__ out)
{
    const int gr = blockIdx.x;
    const int o = threadIdx.x;
    const float invG = 1.0f / (float)N_GRAPHS;
    float m = hstat1[o] * invG;
    float v = hstat1[64 + o] * invG - m * m;
    float b = (t1[gr * 64 + o] - m) * rsqrtf(v + EPS) * gh1[o] + beh1[o];
    float p0 = b * Wc[o * 2];
    float p1 = b * Wc[o * 2 + 1];
#pragma unroll
    for (int off = 32; off > 0; off >>= 1) {
        p0 += __shfl_down(p0, off);
        p1 += __shfl_down(p1, off);
    }
    if (o == 0) {
        out[gr * 2] = p0 + bc[0];
        out[gr * 2 + 1] = p1 + bc[1];
    }
}

// ---------------------------------------------------------------------------
extern "C" void kernel_launch(void* const* d_in, const int* in_sizes, int n_in,
                              void* d_out, int out_size, void* d_ws, size_t ws_size,
                              hipStream_t stream)
{
    const float* x     = (const float*)d_in[0];
    const int*   ei    = (const int*)d_in[1];
    const int*   batch = (const int*)d_in[2];
    const int N = in_sizes[2];
    const int E = in_sizes[1] / 2;
    const int NCHUNK = (N + 1023) / 1024;

    const float *Wk0 = (const float*)d_in[3],  *bk0 = (const float*)d_in[4];
    const float *Wq0 = (const float*)d_in[5],  *bq0 = (const float*)d_in[6];
    const float *Wv0 = (const float*)d_in[7],  *bv0 = (const float*)d_in[8];
    const float *Ws0 = (const float*)d_in[9],  *cb0 = (const float*)d_in[10];
    const float *g0  = (const float*)d_in[11], *be0 = (const float*)d_in[12];
    const float *Wk1 = (const float*)d_in[13], *bk1 = (const float*)d_in[14];
    const float *Wq1 = (const float*)d_in[15], *bq1 = (const float*)d_in[16];
    const float *Wv1 = (const float*)d_in[17], *bv1 = (const float*)d_in[18];
    const float *Ws1 = (const float*)d_in[19], *cb1 = (const float*)d_in[20];
    const float *g1  = (const float*)d_in[21], *be1 = (const float*)d_in[22];
    const float *Wh0 = (const float*)d_in[23], *bh0 = (const float*)d_in[24];
    const float *gh0 = (const float*)d_in[25], *beh0 = (const float*)d_in[26];
    const float *Wh1 = (const float*)d_in[27], *bh1 = (const float*)d_in[28];
    const float *gh1 = (const float*)d_in[29], *beh1 = (const float*)d_in[30];
    const float *Wc  = (const float*)d_in[31], *bc  = (const float*)d_in[32];

    float*    ws = (float*)d_ws;
    unsigned* KS = (unsigned*)ws;                      // N*64 packed fp16 k|s
    unsigned* QV = KS + (size_t)N * 64;                // N*64 packed fp16 q|v
    float*    H  = (float*)(QV + (size_t)N * 64);      // N*64 fp32 (raw y)
    int*   col     = (int*)(H + (size_t)N * 64);       // E
    int*   rowptr  = col + E;             // N+1
    int*   rp1loc  = rowptr + N + 1;      // N
    int*   cursor  = rp1loc + N;          // N (unused; kept for layout)
    int*   psum    = cursor + N;          // 256
    uintptr_t pAl = ((uintptr_t)(psum + 256) + 63) & ~(uintptr_t)63;
    short* BT0h = (short*)pAl;            // 256*128 bf16 hi
    short* BT0l = BT0h + 256 * 128;       // 256*128 bf16 lo
    float* bf0  = (float*)(BT0l + 256 * 128);  // 256
    short* BT1h = (short*)(bf0 + 256);    // 256*64 bf16 hi
    short* BT1l = BT1h + 256 * 64;        // 256*64 bf16 lo
    float* bf1  = (float*)(BT1l + 256 * 64);   // 256
    int*   deg     = (int*)(bf1 + 256);   // N    <-- zero zone starts here
    float* gsumy0 = (float*)(deg + N);    // 128*64
    float* gsumy1 = gsumy0 + 128 * 64;    // 128*64
    float* counts = gsumy1 + 128 * 64;    // 128
    float* stats0 = counts + 128;         // 128
    float* stats1 = stats0 + 128;         // 128
    float* hstat0 = stats1 + 128;         // 256
    float* hstat1 = hstat0 + 256;         // 128
    size_t zbytes = (size_t)N * sizeof(int) +
                    (size_t)(128 * 64 * 2 + 128 * 3 + 256 + 128) * sizeof(float);
    float* t0 = hstat1 + 128;             // 128*128
    float* t1 = t0 + 128 * 128;           // 128*64

    // pos_ aliases KS: lifetimes disjoint (pos_ dies at scatter, KS is born
    // at proj0). E ints (4 MB) <= N*64 uints (25.6 MB).
    int* pos_ = (int*)KS;

    hipMemsetAsync(deg, 0, zbytes, stream);

    // ---- fused prep (deg histogram + slot capture + counts + weights) ----
    prep_kernel<<<400, 256, 0, stream>>>(
        ei, deg, pos_, E, batch, counts, N,
        Wk0, bk0, Wq0, bq0, Wv0, bv0, Ws0, cb0, BT0h, BT0l, bf0,
        Wk1, bk1, Wq1, bq1, Wv1, bv1, Ws1, cb1, BT1h, BT1l, bf1);
    scan1_kernel<<<NCHUNK, 256, 0, stream>>>(deg, rp1loc, psum, N);
    scan2_kernel<<<1, 256, 0, stream>>>(psum, NCHUNK);
    scan3_kernel<<<256, 256, 0, stream>>>(rp1loc, psum, rowptr, N);
    scatter_kernel<<<512, 256, 0, stream>>>(ei, rowptr, pos_, col, E);

    const float invN = 1.0f / (float)N;
    const int projBlocks = (N + 63) / 64;

    // ---- layer 0 ----
    proj_mfma_kernel<128, false><<<projBlocks, 256, 0, stream>>>(
        x, BT0h, BT0l, bf0, nullptr, nullptr, nullptr, invN, KS, QV, N);
    agg_kernel<<<2048, 256, 0, stream>>>(rowptr, col, KS, QV, batch,
                                         H, stats0, gsumy0, N);

    // ---- layer 1 (BN affine computed in-kernel from stats0) ----
    proj_mfma_kernel<64, true><<<projBlocks, 256, 0, stream>>>(
        H, BT1h, BT1l, bf1, stats0, g0, be0, invN, KS, QV, N);
    agg_kernel<<<2048, 256, 0, stream>>>(rowptr, col, KS, QV, batch,
                                         H, stats1, gsumy1, N);

    // ---- head ----
    head1_kernel<<<128, 128, 0, stream>>>(gsumy0, gsumy1, counts,
                                          stats0, stats1, g0, be0, g1, be1,
                                          Wh0, bh0, t0, hstat0, invN);
    head2_kernel<<<128, 64, 0, stream>>>(t0, hstat0, gh0, beh0, Wh1, bh1, t1, hstat1);
    head3_kernel<<<128, 64, 0, stream>>>(t1, hstat1, gh1, beh1, Wc, bc, (float*)d_out);
}